// Round 1
// baseline (444.426 us; speedup 1.0000x reference)
//
#include <hip/hip_runtime.h>
#include <hip/hip_bf16.h>

typedef _Float16 f16;
typedef __attribute__((ext_vector_type(4))) _Float16 f16x4;
typedef __attribute__((ext_vector_type(8))) _Float16 f16x8;
typedef __attribute__((ext_vector_type(4))) float f32x4;

#define MFMA16(a, b, c) __builtin_amdgcn_mfma_f32_16x16x16f16((a), (b), (c), 0, 0, 0)

// ---------------- cast fp32 -> fp16 (vectorized) ----------------
__global__ __launch_bounds__(256) void cast_f32_f16_kernel(
    const float* __restrict__ in, f16* __restrict__ out, int n4) {
  int i = blockIdx.x * 256 + threadIdx.x;
  if (i >= n4) return;
  const float4 v = reinterpret_cast<const float4*>(in)[i];
  f16x4 h;
  h[0] = (f16)v.x; h[1] = (f16)v.y; h[2] = (f16)v.z; h[3] = (f16)v.w;
  reinterpret_cast<f16x4*>(out)[i] = h;
}

// ------------- transpose + cast: src[R][Cc] f32 -> dst[Cc][R] f16 -------------
__global__ __launch_bounds__(256) void transpose_cast_kernel(
    const float* __restrict__ src, f16* __restrict__ dst, int R, int Cc) {
  __shared__ float t[32][33];  // +1 pad: conflict-free column reads
  int tx0 = blockIdx.x * 32, ty0 = blockIdx.y * 32;
  int c = threadIdx.x & 31;
  int r0 = threadIdx.x >> 5;  // 0..7
#pragma unroll
  for (int i = 0; i < 4; i++) {
    int r = r0 + 8 * i;
    t[r][c] = src[(size_t)(ty0 + r) * Cc + tx0 + c];
  }
  __syncthreads();
#pragma unroll
  for (int i = 0; i < 4; i++) {
    int a = r0 + 8 * i;
    dst[(size_t)(tx0 + a) * R + ty0 + c] = (f16)t[c][a];
  }
}

// ---------------- GEMM: C[M][N] = A[M][K] (f16) * Bt[N][K]^T (f16) ----------------
// 128x128 tile, 4 waves (2x2), each wave 64x64 = 4x4 MFMA 16x16x16 tiles, BK=32.
template <bool OUT_F32>
__global__ __launch_bounds__(256) void gemm_f16_kernel(
    const f16* __restrict__ A, const f16* __restrict__ Bt, void* __restrict__ Cout,
    int M, int N, int K) {
  constexpr int BM = 128, BN = 128, BK = 32;
  constexpr int LDL = BK + 8;  // 40 f16 = 80 B row stride: 16B-aligned, spreads banks
  __shared__ f16 Al[BM][LDL];
  __shared__ f16 Bl[BN][LDL];

  const int tn0 = blockIdx.x * BN, tm0 = blockIdx.y * BM;
  const int tid = threadIdx.x;
  const int lane = tid & 63, wid = tid >> 6;
  const int wm = wid >> 1, wn = wid & 1;
  const int lo = lane & 15, hi = lane >> 4;

  f32x4 acc[4][4] = {};

  for (int kt = 0; kt < K; kt += BK) {
    __syncthreads();  // protect LDS from prior-iter readers
#pragma unroll
    for (int i = 0; i < 2; i++) {
      int c = tid + 256 * i;           // 512 chunks of 16B
      int r = c >> 2, off = (c & 3) * 8;
      *(f16x8*)&Al[r][off] = *(const f16x8*)&A[(size_t)(tm0 + r) * K + kt + off];
      *(f16x8*)&Bl[r][off] = *(const f16x8*)&Bt[(size_t)(tn0 + r) * K + kt + off];
    }
    __syncthreads();
#pragma unroll
    for (int ks = 0; ks < 2; ks++) {
      f16x4 af[4], bf[4];
#pragma unroll
      for (int mi = 0; mi < 4; mi++)
        af[mi] = *(const f16x4*)&Al[wm * 64 + mi * 16 + lo][ks * 16 + 4 * hi];
#pragma unroll
      for (int ni = 0; ni < 4; ni++)
        bf[ni] = *(const f16x4*)&Bl[wn * 64 + ni * 16 + lo][ks * 16 + 4 * hi];
#pragma unroll
      for (int mi = 0; mi < 4; mi++)
#pragma unroll
        for (int ni = 0; ni < 4; ni++)
          acc[mi][ni] = MFMA16(af[mi], bf[ni], acc[mi][ni]);
    }
  }

#pragma unroll
  for (int mi = 0; mi < 4; mi++)
#pragma unroll
    for (int ni = 0; ni < 4; ni++)
#pragma unroll
      for (int r = 0; r < 4; r++) {
        int row = tm0 + wm * 64 + mi * 16 + 4 * hi + r;
        int col = tn0 + wn * 64 + ni * 16 + lo;
        float v = acc[mi][ni][r];
        if (OUT_F32)
          ((float*)Cout)[(size_t)row * N + col] = v;
        else
          ((f16*)Cout)[(size_t)row * N + col] = (f16)v;
      }
}

// ---------------- causal flash attention ----------------
// qkv: [B*T][3072] f16 (cols 0..1023 Q, 1024..2047 K, 2048..3071 V; 16 heads x 64)
// y:   [B*T][1024] f16
// grid: (T/64, B*NH); block 256 = 4 waves; wave w owns q rows [q0+16w, q0+16w+16)
__global__ __launch_bounds__(256) void attn_kernel(
    const f16* __restrict__ qkv, f16* __restrict__ y) {
  constexpr int T = 2048, NHD = 3072;
  const int bh = blockIdx.y;
  const int b = bh >> 4, h = bh & 15;
  const int q0 = blockIdx.x * 64;
  const int tid = threadIdx.x;
  const int lane = tid & 63, w = tid >> 6;
  const int lo = lane & 15, hi = lane >> 4;

  const size_t base = (size_t)b * T * NHD + (size_t)h * 64;
  const f16* Q = qkv + base;
  const f16* Kp = qkv + base + 1024;
  const f16* Vp = qkv + base + 2048;

  constexpr int LDK = 64 + 8;  // 144 B rows (16B-aligned writes)
  constexpr int LDV = 64 + 4;  // 136 B rows (8B-aligned reads)
  constexpr int LDP = 64 + 4;
  __shared__ f16 Kl[64][LDK];
  __shared__ f16 Vt[64][LDV];          // V transposed: Vt[hd][key]
  __shared__ f16 Pl[4][16][LDP];       // per-wave P tile [q_rel][key_rel]

  // Q fragments in registers: A[m=lo][k=16*ks+4*hi+j]
  f16x4 qf[4];
  const int qrow = q0 + w * 16 + lo;
#pragma unroll
  for (int ks = 0; ks < 4; ks++)
    qf[ks] = *(const f16x4*)&Q[(size_t)qrow * NHD + ks * 16 + 4 * hi];

  f32x4 oacc[4] = {};
  float m[4], lsum[4];
#pragma unroll
  for (int r = 0; r < 4; r++) { m[r] = -1e30f; lsum[r] = 0.f; }

  const float sc = 0.125f * 1.44269504089f;  // 1/sqrt(64) * log2(e)

  for (int kv0 = 0; kv0 <= q0; kv0 += 64) {
    __syncthreads();
    // stage K tile [key][hd] (vectorized) and Vt [hd][key] (scalar scatter)
#pragma unroll
    for (int i = 0; i < 2; i++) {
      int c = tid + 256 * i;
      int r = c >> 3, off = (c & 7) * 8;
      *(f16x8*)&Kl[r][off] = *(const f16x8*)&Kp[(size_t)(kv0 + r) * NHD + off];
      f16x8 v = *(const f16x8*)&Vp[(size_t)(kv0 + r) * NHD + off];
#pragma unroll
      for (int j = 0; j < 8; j++) Vt[off + j][r] = v[j];
    }
    __syncthreads();

    // S = Q K^T : 4 hd-steps x 4 key-col-tiles
    f32x4 s[4] = {};
#pragma unroll
    for (int ks = 0; ks < 4; ks++) {
#pragma unroll
      for (int ct = 0; ct < 4; ct++) {
        f16x4 kf = *(const f16x4*)&Kl[ct * 16 + lo][ks * 16 + 4 * hi];
        s[ct] = MFMA16(qf[ks], kf, s[ct]);
      }
    }
    // causal mask: only on diagonal tile
    if (kv0 == q0) {
#pragma unroll
      for (int ct = 0; ct < 4; ct++)
#pragma unroll
        for (int r = 0; r < 4; r++) {
          int qr = w * 16 + 4 * hi + r;
          int kc = ct * 16 + lo;
          if (kc > qr) s[ct][r] = -3e38f;
        }
    }
    // online softmax (per-row over this tile's 64 cols, 16-lane group reduce)
    float pv[4][4], alpha[4];
#pragma unroll
    for (int r = 0; r < 4; r++) {
      float t0 = s[0][r] * sc, t1 = s[1][r] * sc, t2 = s[2][r] * sc, t3 = s[3][r] * sc;
      float tm = fmaxf(fmaxf(t0, t1), fmaxf(t2, t3));
      tm = fmaxf(tm, __shfl_xor(tm, 1));
      tm = fmaxf(tm, __shfl_xor(tm, 2));
      tm = fmaxf(tm, __shfl_xor(tm, 4));
      tm = fmaxf(tm, __shfl_xor(tm, 8));
      float mn = fmaxf(m[r], tm);
      float al = exp2f(m[r] - mn);
      float p0 = exp2f(t0 - mn), p1 = exp2f(t1 - mn);
      float p2 = exp2f(t2 - mn), p3 = exp2f(t3 - mn);
      float rs = (p0 + p1) + (p2 + p3);
      rs += __shfl_xor(rs, 1);
      rs += __shfl_xor(rs, 2);
      rs += __shfl_xor(rs, 4);
      rs += __shfl_xor(rs, 8);
      lsum[r] = lsum[r] * al + rs;
      m[r] = mn; alpha[r] = al;
      pv[0][r] = p0; pv[1][r] = p1; pv[2][r] = p2; pv[3][r] = p3;
    }
    // rescale O, spill P to per-wave LDS (D-layout -> A-layout round trip)
#pragma unroll
    for (int ct = 0; ct < 4; ct++)
#pragma unroll
      for (int r = 0; r < 4; r++) {
        oacc[ct][r] *= alpha[r];
        Pl[w][4 * hi + r][ct * 16 + lo] = (f16)pv[ct][r];
      }
    // O += P V : A[m=q=lo][k=key], B[k=key][n=hd] from Vt
#pragma unroll
    for (int ks = 0; ks < 4; ks++) {
      f16x4 pf = *(const f16x4*)&Pl[w][lo][ks * 16 + 4 * hi];
#pragma unroll
      for (int ct = 0; ct < 4; ct++) {
        f16x4 vf = *(const f16x4*)&Vt[ct * 16 + lo][ks * 16 + 4 * hi];
        oacc[ct] = MFMA16(pf, vf, oacc[ct]);
      }
    }
  }

  // epilogue: O / lsum -> y[b*T+q][h*64+hd]
#pragma unroll
  for (int ct = 0; ct < 4; ct++)
#pragma unroll
    for (int r = 0; r < 4; r++) {
      int row = q0 + w * 16 + 4 * hi + r;
      int col = h * 64 + ct * 16 + lo;
      y[((size_t)b * T + row) * 1024 + col] = (f16)(oacc[ct][r] / lsum[r]);
    }
}

extern "C" void kernel_launch(void* const* d_in, const int* in_sizes, int n_in,
                              void* d_out, int out_size, void* d_ws, size_t ws_size,
                              hipStream_t stream) {
  const float* x = (const float*)d_in[0];
  // d_in[1] = causal mask (known tril; unused)
  const float* w_qkv = (const float*)d_in[2];
  const float* w_proj = (const float*)d_in[3];

  constexpr int B = 4, T = 2048, C = 1024, NH = 16;
  constexpr int M = B * T;      // 8192
  constexpr int N1 = 3 * C;     // 3072

  char* ws = (char*)d_ws;
  f16* x16 = (f16*)ws;      ws += (size_t)M * C * 2;    // 16.8 MB
  f16* wqkvT = (f16*)ws;    ws += (size_t)N1 * C * 2;   // 6.3 MB
  f16* wprojT = (f16*)ws;   ws += (size_t)C * C * 2;    // 2.1 MB
  f16* qkvb = (f16*)ws;     ws += (size_t)M * N1 * 2;   // 50.3 MB
  f16* y16 = (f16*)ws;                                  // 16.8 MB

  cast_f32_f16_kernel<<<(M * C / 4 + 255) / 256, 256, 0, stream>>>(x, x16, M * C / 4);
  transpose_cast_kernel<<<dim3(N1 / 32, C / 32), 256, 0, stream>>>(w_qkv, wqkvT, C, N1);
  transpose_cast_kernel<<<dim3(C / 32, C / 32), 256, 0, stream>>>(w_proj, wprojT, C, C);
  gemm_f16_kernel<false><<<dim3(N1 / 128, M / 128), 256, 0, stream>>>(x16, wqkvT, qkvb, M, N1, C);
  attn_kernel<<<dim3(T / 64, B * NH), 256, 0, stream>>>(qkvb, y16);
  gemm_f16_kernel<true><<<dim3(C / 128, M / 128), 256, 0, stream>>>(y16, wprojT, (float*)d_out, M, C, C);
}

// Round 2
// 233.961 us; speedup vs baseline: 1.8996x; 1.8996x over previous
//
#include <hip/hip_runtime.h>
#include <hip/hip_bf16.h>

typedef _Float16 f16;
typedef __attribute__((ext_vector_type(4))) _Float16 f16x4;
typedef __attribute__((ext_vector_type(8))) _Float16 f16x8;
typedef __attribute__((ext_vector_type(4))) float f32x4;

#define MFMA16(a, b, c) __builtin_amdgcn_mfma_f32_16x16x16f16((a), (b), (c), 0, 0, 0)
#define MFMA32(a, b, c) __builtin_amdgcn_mfma_f32_16x16x32_f16((a), (b), (c), 0, 0, 0)
#define GLOAD_LDS16(g, l)                                                        \
  __builtin_amdgcn_global_load_lds((const __attribute__((address_space(1))) void*)(g), \
                                   (__attribute__((address_space(3))) void*)(l), 16, 0, 0)

// ---------------- cast fp32 -> fp16 (vectorized) ----------------
__global__ __launch_bounds__(256) void cast_f32_f16_kernel(
    const float* __restrict__ in, f16* __restrict__ out, int n4) {
  int i = blockIdx.x * 256 + threadIdx.x;
  if (i >= n4) return;
  const float4 v = reinterpret_cast<const float4*>(in)[i];
  f16x4 h;
  h[0] = (f16)v.x; h[1] = (f16)v.y; h[2] = (f16)v.z; h[3] = (f16)v.w;
  reinterpret_cast<f16x4*>(out)[i] = h;
}

// ------------- transpose + cast: src[R][Cc] f32 -> dst[Cc][R] f16 -------------
__global__ __launch_bounds__(256) void transpose_cast_kernel(
    const float* __restrict__ src, f16* __restrict__ dst, int R, int Cc) {
  __shared__ float t[32][33];
  int tx0 = blockIdx.x * 32, ty0 = blockIdx.y * 32;
  int c = threadIdx.x & 31;
  int r0 = threadIdx.x >> 5;
#pragma unroll
  for (int i = 0; i < 4; i++) {
    int r = r0 + 8 * i;
    t[r][c] = src[(size_t)(ty0 + r) * Cc + tx0 + c];
  }
  __syncthreads();
#pragma unroll
  for (int i = 0; i < 4; i++) {
    int a = r0 + 8 * i;
    dst[(size_t)(tx0 + a) * R + ty0 + c] = (f16)t[c][a];
  }
}

// ---------------- GEMM (m97 structure): C[M][N] = A[M][K] * Bt[N][K]^T ----------------
// 128x128 tile, 4 waves (2x2), 16x16x32 MFMA, BK=32, linear LDS + global_load_lds w16.
template <bool OUT_F32>
__global__ __launch_bounds__(256) void gemm_f16_kernel(
    const f16* __restrict__ A, const f16* __restrict__ Bt, void* __restrict__ Cout,
    int M, int N, int K) {
  constexpr int BK = 32;
  __shared__ f16 Al[128 * BK];
  __shared__ f16 Bl[128 * BK];

  const int tid = threadIdx.x;
  const int lane = tid & 63, wid = tid >> 6;
  const int wm = wid >> 1, wn = wid & 1;
  const int lo = lane & 15, hi = lane >> 4;
  const int tn0 = blockIdx.x * 128, tm0 = blockIdx.y * 128;

  f32x4 acc[4][4] = {};

  const int r1 = tid >> 2, o1 = (tid & 3) * 8;
  const int c2 = tid + 256, r2 = c2 >> 2, o2 = (c2 & 3) * 8;

  for (int kt = 0; kt < K; kt += BK) {
    __syncthreads();
    GLOAD_LDS16(&A[(size_t)(tm0 + r1) * K + kt + o1], &Al[tid * 8]);
    GLOAD_LDS16(&A[(size_t)(tm0 + r2) * K + kt + o2], &Al[c2 * 8]);
    GLOAD_LDS16(&Bt[(size_t)(tn0 + r1) * K + kt + o1], &Bl[tid * 8]);
    GLOAD_LDS16(&Bt[(size_t)(tn0 + r2) * K + kt + o2], &Bl[c2 * 8]);
    __syncthreads();

    f16x8 af[4], bf[4];
#pragma unroll
    for (int mi = 0; mi < 4; mi++)
      af[mi] = *(const f16x8*)&Al[(wm * 64 + mi * 16 + lo) * BK + 8 * hi];
#pragma unroll
    for (int ni = 0; ni < 4; ni++)
      bf[ni] = *(const f16x8*)&Bl[(wn * 64 + ni * 16 + lo) * BK + 8 * hi];
#pragma unroll
    for (int mi = 0; mi < 4; mi++)
#pragma unroll
      for (int ni = 0; ni < 4; ni++)
        acc[mi][ni] = MFMA32(af[mi], bf[ni], acc[mi][ni]);
  }

#pragma unroll
  for (int mi = 0; mi < 4; mi++)
#pragma unroll
    for (int ni = 0; ni < 4; ni++)
#pragma unroll
      for (int r = 0; r < 4; r++) {
        int row = tm0 + wm * 64 + mi * 16 + 4 * hi + r;
        int col = tn0 + wn * 64 + ni * 16 + lo;
        float v = acc[mi][ni][r];
        if (OUT_F32)
          ((float*)Cout)[(size_t)row * N + col] = v;
        else
          ((f16*)Cout)[(size_t)row * N + col] = (f16)v;
      }
}

// ---------------- causal flash attention (swapped QK^T, P in registers) ----------------
// qkv: [B*T][3072] f16; y: [B*T][1024] f16
// grid: (B*NH, T/128); block 256 = 4 waves; wave w owns q rows [q0+32w, q0+32w+32)
// Per lane: q = lane&15 (within 16-row sub-tile), keys/hd indexed by hi=lane>>4.
__global__ __launch_bounds__(256) void attn_kernel(
    const f16* __restrict__ qkv, f16* __restrict__ y) {
  constexpr int T = 2048, NHD = 3072, LDV = 68, LDO = 72;
  const int bh = blockIdx.x;
  const int b = bh >> 4, h = bh & 15;
  const int qt = (int)gridDim.y - 1 - blockIdx.y;  // big tiles dispatched first
  const int q0 = qt * 128;
  const int tid = threadIdx.x;
  const int lane = tid & 63, w = tid >> 6;
  const int lo = lane & 15, hi = lane >> 4;

  const size_t base = (size_t)b * T * NHD + (size_t)h * 64;
  const f16* Qp = qkv + base;
  const f16* Kp = qkv + base + 1024;
  const f16* Vp = qkv + base + 2048;

  __shared__ f16 Kl[64 * 64];      // K tile, row-major, XOR-swizzled 16B slots
  __shared__ f16 Vt[64][LDV];      // V transposed: Vt[hd][key]
  __shared__ f16 Ol[128][LDO];     // output transpose buffer

  const int qbw = q0 + w * 32;

  // Q fragments (B-operand of swapped QK^T): b[j] = Q[q=lo][hd = ks*32 + 8*hi + j]
  f16x8 qf[2][2];
#pragma unroll
  for (int sub = 0; sub < 2; sub++) {
    const f16* qrowp = Qp + (size_t)(qbw + sub * 16 + lo) * NHD;
#pragma unroll
    for (int ks = 0; ks < 2; ks++)
      qf[sub][ks] = *(const f16x8*)&qrowp[ks * 32 + 8 * hi];
  }

  f32x4 oacc[2][4] = {};                     // O^T[hd=ct*16+4hi+r][q=lo]
  float mreg[2] = {-1e30f, -1e30f};
  float lsum[2] = {0.f, 0.f};
  const float sc = 0.125f * 1.44269504089f;  // 1/sqrt(64) * log2(e)

  // staging coords
  const int vr1 = tid >> 3, vo1 = (tid & 7) * 8;
  const int vc2 = tid + 256, vr2 = vc2 >> 3, vo2 = (vc2 & 7) * 8;
  const int ksl1 = (tid & 7) ^ (vr1 & 7);    // pre-swizzled K source slot
  const int ksl2 = (vc2 & 7) ^ (vr2 & 7);

  for (int kv0 = 0; kv0 < q0 + 128; kv0 += 64) {
    __syncthreads();
    // K via global_load_lds (linear dest, inverse-swizzled source)
    GLOAD_LDS16(&Kp[(size_t)(kv0 + vr1) * NHD + ksl1 * 8], &Kl[tid * 8]);
    GLOAD_LDS16(&Kp[(size_t)(kv0 + vr2) * NHD + ksl2 * 8], &Kl[vc2 * 8]);
    // V transposed (reg-staged scatter)
    {
      f16x8 v1 = *(const f16x8*)&Vp[(size_t)(kv0 + vr1) * NHD + vo1];
      f16x8 v2 = *(const f16x8*)&Vp[(size_t)(kv0 + vr2) * NHD + vo2];
#pragma unroll
      for (int j = 0; j < 8; j++) Vt[vo1 + j][vr1] = v1[j];
#pragma unroll
      for (int j = 0; j < 8; j++) Vt[vo2 + j][vr2] = v2[j];
    }
    __syncthreads();

    if (kv0 > qbw + 31) continue;  // this wave fully masked (barriers already passed)

    // K fragments (A-operand): a[j] = K[key=ct*16+lo][hd = ks*32 + 8*hi + j], swizzled slot
    f16x8 kf[2][4];
#pragma unroll
    for (int ks = 0; ks < 2; ks++)
#pragma unroll
      for (int ct = 0; ct < 4; ct++) {
        int key = ct * 16 + lo;
        kf[ks][ct] = *(const f16x8*)&Kl[key * 64 + ((ks * 4 + hi) ^ (key & 7)) * 8];
      }

#pragma unroll
    for (int sub = 0; sub < 2; sub++) {
      const int qb = qbw + sub * 16;
      if (kv0 <= qb + 15) {
        // S^T[key][q]: s[ct][r] = S[q=lo][key = kv0 + ct*16 + 4*hi + r]
        f32x4 s[4] = {};
#pragma unroll
        for (int ks = 0; ks < 2; ks++)
#pragma unroll
          for (int ct = 0; ct < 4; ct++)
            s[ct] = MFMA32(kf[ks][ct], qf[sub][ks], s[ct]);

        if (kv0 + 63 > qb) {  // diagonal tile: causal mask
          const int q = qb + lo;
#pragma unroll
          for (int ct = 0; ct < 4; ct++)
#pragma unroll
            for (int r = 0; r < 4; r++)
              if (kv0 + ct * 16 + 4 * hi + r > q) s[ct][r] = -3.0e38f;
        }
        // online softmax: scale, in-lane reduce 16, cross-hi shuffles
        float mt = -3.0e38f;
#pragma unroll
        for (int ct = 0; ct < 4; ct++)
#pragma unroll
          for (int r = 0; r < 4; r++) {
            float v = s[ct][r] * sc;
            s[ct][r] = v;
            mt = fmaxf(mt, v);
          }
        mt = fmaxf(mt, __shfl_xor(mt, 16));
        mt = fmaxf(mt, __shfl_xor(mt, 32));
        const float mn = fmaxf(mreg[sub], mt);
        const float al = exp2f(mreg[sub] - mn);
        mreg[sub] = mn;
        float rs = 0.f;
        f16x4 pb[4];  // P^T fragments, directly PV's B-operand
#pragma unroll
        for (int ct = 0; ct < 4; ct++)
#pragma unroll
          for (int r = 0; r < 4; r++) {
            float p = exp2f(s[ct][r] - mn);
            rs += p;
            pb[ct][r] = (f16)p;
          }
        rs += __shfl_xor(rs, 16);
        rs += __shfl_xor(rs, 32);
        lsum[sub] = lsum[sub] * al + rs;
#pragma unroll
        for (int ct = 0; ct < 4; ct++)
#pragma unroll
          for (int r = 0; r < 4; r++) oacc[sub][ct][r] *= al;
        // O^T += V^T P^T : A-frag a[j] = Vt[hd=ct*16+lo][key = kk*16+4*hi+j]
#pragma unroll
        for (int kk = 0; kk < 4; kk++)
#pragma unroll
          for (int ct = 0; ct < 4; ct++) {
            f16x4 vf = *(const f16x4*)&Vt[ct * 16 + lo][kk * 16 + 4 * hi];
            oacc[sub][ct] = MFMA16(vf, pb[kk], oacc[sub][ct]);
          }
      }
    }
  }

  // epilogue: O^T -> LDS transpose -> coalesced stores
  __syncthreads();
#pragma unroll
  for (int sub = 0; sub < 2; sub++) {
    const float inv = 1.f / lsum[sub];
#pragma unroll
    for (int ct = 0; ct < 4; ct++)
#pragma unroll
      for (int r = 0; r < 4; r++)
        Ol[w * 32 + sub * 16 + lo][ct * 16 + 4 * hi + r] = (f16)(oacc[sub][ct][r] * inv);
  }
  __syncthreads();
#pragma unroll
  for (int i = 0; i < 4; i++) {
    int idx = tid + 256 * i;
    int qq = idx >> 3, ch = idx & 7;
    *(f16x8*)&y[((size_t)b * T + q0 + qq) * 1024 + (size_t)h * 64 + ch * 8] =
        *(const f16x8*)&Ol[qq][ch * 8];
  }
}

extern "C" void kernel_launch(void* const* d_in, const int* in_sizes, int n_in,
                              void* d_out, int out_size, void* d_ws, size_t ws_size,
                              hipStream_t stream) {
  const float* x = (const float*)d_in[0];
  const float* w_qkv = (const float*)d_in[2];
  const float* w_proj = (const float*)d_in[3];

  constexpr int B = 4, T = 2048, C = 1024, NH = 16;
  constexpr int M = B * T;   // 8192
  constexpr int N1 = 3 * C;  // 3072

  char* ws = (char*)d_ws;
  f16* x16 = (f16*)ws;    ws += (size_t)M * C * 2;
  f16* wqkvT = (f16*)ws;  ws += (size_t)N1 * C * 2;
  f16* wprojT = (f16*)ws; ws += (size_t)C * C * 2;
  f16* qkvb = (f16*)ws;   ws += (size_t)M * N1 * 2;
  f16* y16 = (f16*)ws;

  cast_f32_f16_kernel<<<(M * C / 4 + 255) / 256, 256, 0, stream>>>(x, x16, M * C / 4);
  transpose_cast_kernel<<<dim3(N1 / 32, C / 32), 256, 0, stream>>>(w_qkv, wqkvT, C, N1);
  transpose_cast_kernel<<<dim3(C / 32, C / 32), 256, 0, stream>>>(w_proj, wprojT, C, C);
  gemm_f16_kernel<false><<<dim3(N1 / 128, M / 128), 256, 0, stream>>>(x16, wqkvT, qkvb, M, N1, C);
  attn_kernel<<<dim3(B * NH, T / 128), 256, 0, stream>>>(qkvb, y16);
  gemm_f16_kernel<true><<<dim3(C / 128, M / 128), 256, 0, stream>>>(y16, wprojT, (float*)d_out, M, C, C);
}

// Round 3
// 223.453 us; speedup vs baseline: 1.9889x; 1.0470x over previous
//
#include <hip/hip_runtime.h>
#include <hip/hip_bf16.h>

typedef _Float16 f16;
typedef __attribute__((ext_vector_type(4))) _Float16 f16x4;
typedef __attribute__((ext_vector_type(8))) _Float16 f16x8;
typedef __attribute__((ext_vector_type(4))) float f32x4;

#define MFMA16(a, b, c) __builtin_amdgcn_mfma_f32_16x16x16f16((a), (b), (c), 0, 0, 0)
#define MFMA32(a, b, c) __builtin_amdgcn_mfma_f32_16x16x32_f16((a), (b), (c), 0, 0, 0)
#define GLOAD_LDS16(g, l)                                                        \
  __builtin_amdgcn_global_load_lds((const __attribute__((address_space(1))) void*)(g), \
                                   (__attribute__((address_space(3))) void*)(l), 16, 0, 0)

// ---------------- cast fp32 -> fp16 (vectorized) ----------------
__global__ __launch_bounds__(256) void cast_f32_f16_kernel(
    const float* __restrict__ in, f16* __restrict__ out, int n4) {
  int i = blockIdx.x * 256 + threadIdx.x;
  if (i >= n4) return;
  const float4 v = reinterpret_cast<const float4*>(in)[i];
  f16x4 h;
  h[0] = (f16)v.x; h[1] = (f16)v.y; h[2] = (f16)v.z; h[3] = (f16)v.w;
  reinterpret_cast<f16x4*>(out)[i] = h;
}

// ------------- transpose + cast: src[R][Cc] f32 -> dst[Cc][R] f16 -------------
__global__ __launch_bounds__(256) void transpose_cast_kernel(
    const float* __restrict__ src, f16* __restrict__ dst, int R, int Cc) {
  __shared__ float t[32][33];
  int tx0 = blockIdx.x * 32, ty0 = blockIdx.y * 32;
  int c = threadIdx.x & 31;
  int r0 = threadIdx.x >> 5;
#pragma unroll
  for (int i = 0; i < 4; i++) {
    int r = r0 + 8 * i;
    t[r][c] = src[(size_t)(ty0 + r) * Cc + tx0 + c];
  }
  __syncthreads();
#pragma unroll
  for (int i = 0; i < 4; i++) {
    int a = r0 + 8 * i;
    dst[(size_t)(tx0 + a) * R + ty0 + c] = (f16)t[c][a];
  }
}

// ---------------- GEMM (m97 structure): C[M][N] = A[M][K] * Bt[N][K]^T ----------------
template <bool OUT_F32>
__global__ __launch_bounds__(256) void gemm_f16_kernel(
    const f16* __restrict__ A, const f16* __restrict__ Bt, void* __restrict__ Cout,
    int M, int N, int K) {
  constexpr int BK = 32;
  __shared__ f16 Al[128 * BK];
  __shared__ f16 Bl[128 * BK];

  const int tid = threadIdx.x;
  const int lane = tid & 63, wid = tid >> 6;
  const int wm = wid >> 1, wn = wid & 1;
  const int lo = lane & 15, hi = lane >> 4;
  const int tn0 = blockIdx.x * 128, tm0 = blockIdx.y * 128;

  f32x4 acc[4][4] = {};

  const int r1 = tid >> 2, o1 = (tid & 3) * 8;
  const int c2 = tid + 256, r2 = c2 >> 2, o2 = (c2 & 3) * 8;

  for (int kt = 0; kt < K; kt += BK) {
    __syncthreads();
    GLOAD_LDS16(&A[(size_t)(tm0 + r1) * K + kt + o1], &Al[tid * 8]);
    GLOAD_LDS16(&A[(size_t)(tm0 + r2) * K + kt + o2], &Al[c2 * 8]);
    GLOAD_LDS16(&Bt[(size_t)(tn0 + r1) * K + kt + o1], &Bl[tid * 8]);
    GLOAD_LDS16(&Bt[(size_t)(tn0 + r2) * K + kt + o2], &Bl[c2 * 8]);
    __syncthreads();

    f16x8 af[4], bf[4];
#pragma unroll
    for (int mi = 0; mi < 4; mi++)
      af[mi] = *(const f16x8*)&Al[(wm * 64 + mi * 16 + lo) * BK + 8 * hi];
#pragma unroll
    for (int ni = 0; ni < 4; ni++)
      bf[ni] = *(const f16x8*)&Bl[(wn * 64 + ni * 16 + lo) * BK + 8 * hi];
#pragma unroll
    for (int mi = 0; mi < 4; mi++)
#pragma unroll
      for (int ni = 0; ni < 4; ni++)
        acc[mi][ni] = MFMA32(af[mi], bf[ni], acc[mi][ni]);
  }

#pragma unroll
  for (int mi = 0; mi < 4; mi++)
#pragma unroll
    for (int ni = 0; ni < 4; ni++)
#pragma unroll
      for (int r = 0; r < 4; r++) {
        int row = tm0 + wm * 64 + mi * 16 + 4 * hi + r;
        int col = tn0 + wn * 64 + ni * 16 + lo;
        float v = acc[mi][ni][r];
        if (OUT_F32)
          ((float*)Cout)[(size_t)row * N + col] = v;
        else
          ((f16*)Cout)[(size_t)row * N + col] = (f16)v;
      }
}

// ---------------- causal flash attention (paired q-tiles, uniform work) ----------------
// grid: (B*NH, 16 pairs); block 256 = 4 waves.
// Block handles q-tiles {p, 31-p} (64 rows each); wave w owns rows [t*64+16w, +16) of each.
// Work per block = (p+1)+(32-p) = 33 sub-steps, constant -> no tail imbalance.
__global__ __launch_bounds__(256, 4) void attn_kernel(
    const f16* __restrict__ qkv, f16* __restrict__ y) {
  constexpr int T = 2048, NHD = 3072, LDV = 68, LDO = 72;
  const int bh = blockIdx.x;
  const int b = bh >> 4, h = bh & 15;
  const int pr = blockIdx.y;  // pair index 0..15
  const int tid = threadIdx.x;
  const int lane = tid & 63, w = tid >> 6;
  const int lo = lane & 15, hi = lane >> 4;

  const size_t base = (size_t)b * T * NHD + (size_t)h * 64;
  const f16* Qp = qkv + base;
  const f16* Kp = qkv + base + 1024;
  const f16* Vp = qkv + base + 2048;

  // LDS union: K(8192B) + Vt(8704B) during loop; Ol(9216B) at epilogue
  __shared__ __align__(16) char smem[8192 + 64 * LDV * 2];
  f16* Kl = (f16*)smem;                        // [64][64], XOR-swizzled 16B slots
  f16 (*Vt)[LDV] = (f16(*)[LDV])(smem + 8192); // V transposed [hd][key]
  f16 (*Ol)[LDO] = (f16(*)[LDO])smem;          // epilogue transpose buffer

  const int tile[2] = {pr, 31 - pr};
  const int qb[2] = {tile[0] * 64 + w * 16, tile[1] * 64 + w * 16};

  // Q fragments, pre-scaled by 1/sqrt(64)*log2(e)
  const float scf = 0.125f * 1.44269504089f;
  f16x8 qf[2][2];
#pragma unroll
  for (int s = 0; s < 2; s++) {
    const f16* qrow = Qp + (size_t)(qb[s] + lo) * NHD;
#pragma unroll
    for (int ks = 0; ks < 2; ks++) {
      f16x8 v = *(const f16x8*)&qrow[ks * 32 + 8 * hi];
#pragma unroll
      for (int j = 0; j < 8; j++) v[j] = (f16)((float)v[j] * scf);
      qf[s][ks] = v;
    }
  }

  f32x4 oacc[2][4] = {};  // O^T[hd=ct*16+4hi+r][q=lo] per sub
  float mreg[2] = {-1e30f, -1e30f};
  float lsum[2] = {0.f, 0.f};

  const int vr1 = tid >> 3, vo1 = (tid & 7) * 8;
  const int vc2 = tid + 256, vr2 = vc2 >> 3, vo2 = (vc2 & 7) * 8;
  const int ksl1 = (tid & 7) ^ (vr1 & 7);
  const int ksl2 = (vc2 & 7) ^ (vr2 & 7);

  const int nkv = (32 - pr) * 64;
  for (int kv0 = 0; kv0 < nkv; kv0 += 64) {
    __syncthreads();
    GLOAD_LDS16(&Kp[(size_t)(kv0 + vr1) * NHD + ksl1 * 8], &Kl[tid * 8]);
    GLOAD_LDS16(&Kp[(size_t)(kv0 + vr2) * NHD + ksl2 * 8], &Kl[vc2 * 8]);
    {
      f16x8 v1 = *(const f16x8*)&Vp[(size_t)(kv0 + vr1) * NHD + vo1];
      f16x8 v2 = *(const f16x8*)&Vp[(size_t)(kv0 + vr2) * NHD + vo2];
#pragma unroll
      for (int j = 0; j < 8; j++) Vt[vo1 + j][vr1] = v1[j];
#pragma unroll
      for (int j = 0; j < 8; j++) Vt[vo2 + j][vr2] = v2[j];
    }
    __syncthreads();

    // K fragments (A-operand): a[j] = K[key=ct*16+lo][hd=ks*32+8*hi+j]
    f16x8 kf[2][4];
#pragma unroll
    for (int ks = 0; ks < 2; ks++)
#pragma unroll
      for (int ct = 0; ct < 4; ct++) {
        int key = ct * 16 + lo;
        kf[ks][ct] = *(const f16x8*)&Kl[key * 64 + ((ks * 4 + hi) ^ (key & 7)) * 8];
      }

#pragma unroll
    for (int s = 0; s < 2; s++) {
      if (kv0 > qb[s] + 15) continue;  // sub fully masked
      // S^T (pre-scaled): s_[ct][r] = S[q=lo][key = kv0 + ct*16 + 4*hi + r]
      f32x4 s_[4] = {};
#pragma unroll
      for (int ks = 0; ks < 2; ks++)
#pragma unroll
        for (int ct = 0; ct < 4; ct++)
          s_[ct] = MFMA32(kf[ks][ct], qf[s][ks], s_[ct]);

      if (kv0 + 63 > qb[s]) {  // diagonal tile: causal mask
        const int q = qb[s] + lo;
#pragma unroll
        for (int ct = 0; ct < 4; ct++)
#pragma unroll
          for (int r = 0; r < 4; r++)
            if (kv0 + ct * 16 + 4 * hi + r > q) s_[ct][r] = -3.0e38f;
      }
      // row max (16 in-lane + 2 shuffles)
      float mt = -3.0e38f;
#pragma unroll
      for (int ct = 0; ct < 4; ct++)
        mt = fmaxf(mt, fmaxf(fmaxf(s_[ct][0], s_[ct][1]), fmaxf(s_[ct][2], s_[ct][3])));
      mt = fmaxf(mt, __shfl_xor(mt, 16));
      mt = fmaxf(mt, __shfl_xor(mt, 32));
      // defer-max (T13): skip rescale when tile max grew < 8 (log2 units)
      float mn = mreg[s];
      if (!__all(mt <= mn + 8.f)) {
        mn = fmaxf(mn, mt);
        const float al = exp2f(mreg[s] - mn);
        mreg[s] = mn;
        lsum[s] *= al;
#pragma unroll
        for (int ct = 0; ct < 4; ct++)
#pragma unroll
          for (int r = 0; r < 4; r++) oacc[s][ct][r] *= al;
      }
      float rs = 0.f;
      f16x4 pb[4];  // P^T fragments -> PV B-operand
#pragma unroll
      for (int ct = 0; ct < 4; ct++)
#pragma unroll
        for (int r = 0; r < 4; r++) {
          float p = exp2f(s_[ct][r] - mn);
          rs += p;
          pb[ct][r] = (f16)p;
        }
      rs += __shfl_xor(rs, 16);
      rs += __shfl_xor(rs, 32);
      lsum[s] += rs;
      // O^T += V^T P^T
#pragma unroll
      for (int kk = 0; kk < 4; kk++)
#pragma unroll
        for (int ct = 0; ct < 4; ct++) {
          f16x4 vf = *(const f16x4*)&Vt[ct * 16 + lo][kk * 16 + 4 * hi];
          oacc[s][ct] = MFMA16(vf, pb[kk], oacc[s][ct]);
        }
    }
  }

  // epilogue: per sub-group, transpose via LDS then coalesced stores
#pragma unroll
  for (int s = 0; s < 2; s++) {
    __syncthreads();  // Kl/Vt (or prior Ol reads) dead before overwrite
    const float inv = 1.f / lsum[s];
#pragma unroll
    for (int ct = 0; ct < 4; ct++) {
      f16x4 o4;
#pragma unroll
      for (int r = 0; r < 4; r++) o4[r] = (f16)(oacc[s][ct][r] * inv);
      *(f16x4*)&Ol[w * 16 + lo][ct * 16 + 4 * hi] = o4;
    }
    __syncthreads();
#pragma unroll
    for (int i = 0; i < 2; i++) {
      int idx = tid + 256 * i;
      int qq = idx >> 3, ch = idx & 7;
      *(f16x8*)&y[((size_t)b * T + tile[s] * 64 + qq) * 1024 + (size_t)h * 64 + ch * 8] =
          *(const f16x8*)&Ol[qq][ch * 8];
    }
  }
}

extern "C" void kernel_launch(void* const* d_in, const int* in_sizes, int n_in,
                              void* d_out, int out_size, void* d_ws, size_t ws_size,
                              hipStream_t stream) {
  const float* x = (const float*)d_in[0];
  const float* w_qkv = (const float*)d_in[2];
  const float* w_proj = (const float*)d_in[3];

  constexpr int B = 4, T = 2048, C = 1024, NH = 16;
  constexpr int M = B * T;   // 8192
  constexpr int N1 = 3 * C;  // 3072

  char* ws = (char*)d_ws;
  f16* x16 = (f16*)ws;    ws += (size_t)M * C * 2;
  f16* wqkvT = (f16*)ws;  ws += (size_t)N1 * C * 2;
  f16* wprojT = (f16*)ws; ws += (size_t)C * C * 2;
  f16* qkvb = (f16*)ws;   ws += (size_t)M * N1 * 2;
  f16* y16 = (f16*)ws;

  cast_f32_f16_kernel<<<(M * C / 4 + 255) / 256, 256, 0, stream>>>(x, x16, M * C / 4);
  transpose_cast_kernel<<<dim3(N1 / 32, C / 32), 256, 0, stream>>>(w_qkv, wqkvT, C, N1);
  transpose_cast_kernel<<<dim3(C / 32, C / 32), 256, 0, stream>>>(w_proj, wprojT, C, C);
  gemm_f16_kernel<false><<<dim3(N1 / 128, M / 128), 256, 0, stream>>>(x16, wqkvT, qkvb, M, N1, C);
  attn_kernel<<<dim3(B * NH, 16), 256, 0, stream>>>(qkvb, y16);
  gemm_f16_kernel<true><<<dim3(C / 128, M / 128), 256, 0, stream>>>(y16, wprojT, (float*)d_out, M, C, C);
}

// Round 4
// 203.347 us; speedup vs baseline: 2.1856x; 1.0989x over previous
//
#include <hip/hip_runtime.h>
#include <hip/hip_bf16.h>

typedef _Float16 f16;
typedef __attribute__((ext_vector_type(4))) _Float16 f16x4;
typedef __attribute__((ext_vector_type(8))) _Float16 f16x8;
typedef __attribute__((ext_vector_type(4))) float f32x4;

#define MFMA16(a, b, c) __builtin_amdgcn_mfma_f32_16x16x16f16((a), (b), (c), 0, 0, 0)
#define MFMA32(a, b, c) __builtin_amdgcn_mfma_f32_16x16x32_f16((a), (b), (c), 0, 0, 0)
#define GLOAD_LDS16(g, l)                                                        \
  __builtin_amdgcn_global_load_lds((const __attribute__((address_space(1))) void*)(g), \
                                   (__attribute__((address_space(3))) void*)(l), 16, 0, 0)
typedef const __attribute__((address_space(3))) char* lds_cp;
#define TR16(dst, addr, imm) \
  asm volatile("ds_read_b64_tr_b16 %0, %1 offset:" imm : "=v"(dst) : "v"(addr))

// ---------------- cast fp32 -> fp16 (vectorized) ----------------
__global__ __launch_bounds__(256) void cast_f32_f16_kernel(
    const float* __restrict__ in, f16* __restrict__ out, int n4) {
  int i = blockIdx.x * 256 + threadIdx.x;
  if (i >= n4) return;
  const float4 v = reinterpret_cast<const float4*>(in)[i];
  f16x4 h;
  h[0] = (f16)v.x; h[1] = (f16)v.y; h[2] = (f16)v.z; h[3] = (f16)v.w;
  reinterpret_cast<f16x4*>(out)[i] = h;
}

// ------------- transpose + cast: src[R][Cc] f32 -> dst[Cc][R] f16 -------------
__global__ __launch_bounds__(256) void transpose_cast_kernel(
    const float* __restrict__ src, f16* __restrict__ dst, int R, int Cc) {
  __shared__ float t[32][33];
  int tx0 = blockIdx.x * 32, ty0 = blockIdx.y * 32;
  int c = threadIdx.x & 31;
  int r0 = threadIdx.x >> 5;
#pragma unroll
  for (int i = 0; i < 4; i++) {
    int r = r0 + 8 * i;
    t[r][c] = src[(size_t)(ty0 + r) * Cc + tx0 + c];
  }
  __syncthreads();
#pragma unroll
  for (int i = 0; i < 4; i++) {
    int a = r0 + 8 * i;
    dst[(size_t)(tx0 + a) * R + ty0 + c] = (f16)t[c][a];
  }
}

// ---------------- GEMM (m97 structure): C[M][N] = A[M][K] * Bt[N][K]^T ----------------
template <bool OUT_F32>
__global__ __launch_bounds__(256) void gemm_f16_kernel(
    const f16* __restrict__ A, const f16* __restrict__ Bt, void* __restrict__ Cout,
    int M, int N, int K) {
  constexpr int BK = 32;
  __shared__ f16 Al[128 * BK];
  __shared__ f16 Bl[128 * BK];

  const int tid = threadIdx.x;
  const int lane = tid & 63, wid = tid >> 6;
  const int wm = wid >> 1, wn = wid & 1;
  const int lo = lane & 15, hi = lane >> 4;
  const int tn0 = blockIdx.x * 128, tm0 = blockIdx.y * 128;

  f32x4 acc[4][4] = {};

  const int r1 = tid >> 2, o1 = (tid & 3) * 8;
  const int c2 = tid + 256, r2 = c2 >> 2, o2 = (c2 & 3) * 8;

  for (int kt = 0; kt < K; kt += BK) {
    __syncthreads();
    GLOAD_LDS16(&A[(size_t)(tm0 + r1) * K + kt + o1], &Al[tid * 8]);
    GLOAD_LDS16(&A[(size_t)(tm0 + r2) * K + kt + o2], &Al[c2 * 8]);
    GLOAD_LDS16(&Bt[(size_t)(tn0 + r1) * K + kt + o1], &Bl[tid * 8]);
    GLOAD_LDS16(&Bt[(size_t)(tn0 + r2) * K + kt + o2], &Bl[c2 * 8]);
    __syncthreads();

    f16x8 af[4], bf[4];
#pragma unroll
    for (int mi = 0; mi < 4; mi++)
      af[mi] = *(const f16x8*)&Al[(wm * 64 + mi * 16 + lo) * BK + 8 * hi];
#pragma unroll
    for (int ni = 0; ni < 4; ni++)
      bf[ni] = *(const f16x8*)&Bl[(wn * 64 + ni * 16 + lo) * BK + 8 * hi];
#pragma unroll
    for (int mi = 0; mi < 4; mi++)
#pragma unroll
      for (int ni = 0; ni < 4; ni++)
        acc[mi][ni] = MFMA32(af[mi], bf[ni], acc[mi][ni]);
  }

#pragma unroll
  for (int mi = 0; mi < 4; mi++)
#pragma unroll
    for (int ni = 0; ni < 4; ni++)
#pragma unroll
      for (int r = 0; r < 4; r++) {
        int row = tm0 + wm * 64 + mi * 16 + 4 * hi + r;
        int col = tn0 + wn * 64 + ni * 16 + lo;
        float v = acc[mi][ni][r];
        if (OUT_F32)
          ((float*)Cout)[(size_t)row * N + col] = v;
        else
          ((f16*)Cout)[(size_t)row * N + col] = (f16)v;
      }
}

// ---------------- causal flash attention ----------------
// Paired q-tiles {p, 31-p}; double-buffered K/V; V in blocked [hd/16][key/4][4][16]
// LDS layout staged by global_load_lds and consumed via ds_read_b64_tr_b16.
// grid: (B*NH, 16); block 256 = 4 waves; wave w owns rows [tile*64+16w, +16) of each tile.
__global__ __launch_bounds__(256, 4) void attn_kernel(
    const f16* __restrict__ qkv, f16* __restrict__ y) {
  constexpr int T = 2048, NHD = 3072, LDO = 72;
  const int bh = blockIdx.x;
  const int b = bh >> 4, h = bh & 15;
  const int pr = blockIdx.y;  // pair index 0..15
  const int tid = threadIdx.x;
  const int lane = tid & 63, w = tid >> 6;
  const int lo = lane & 15, hi = lane >> 4;

  const size_t base = (size_t)b * T * NHD + (size_t)h * 64;
  const f16* Qp = qkv + base;
  const f16* Kp = qkv + base + 1024;
  const f16* Vp = qkv + base + 2048;

  // [K0 8K][K1 8K][V0 8K][V1 8K]; epilogue Ol aliases the front.
  __shared__ __align__(16) char smem[32768];
  f16 (*Ol)[LDO] = (f16(*)[LDO])smem;

  const int tile[2] = {pr, 31 - pr};
  const int qb[2] = {tile[0] * 64 + w * 16, tile[1] * 64 + w * 16};

  // Q fragments pre-scaled by 1/sqrt(64)*log2(e)
  const float scf = 0.125f * 1.44269504089f;
  f16x8 qf[2][2];
#pragma unroll
  for (int s = 0; s < 2; s++) {
    const f16* qrow = Qp + (size_t)(qb[s] + lo) * NHD;
#pragma unroll
    for (int ks = 0; ks < 2; ks++) {
      f16x8 v = *(const f16x8*)&qrow[ks * 32 + 8 * hi];
#pragma unroll
      for (int j = 0; j < 8; j++) v[j] = (f16)((float)v[j] * scf);
      qf[s][ks] = v;
    }
  }

  f32x4 oacc[2][4] = {};  // O^T[hd=ct*16+4hi+r][q=lo]
  float mreg[2] = {-1e30f, -1e30f};
  float lsum[2] = {0.f, 0.f};

  // staging coords
  const int kr = tid >> 3;                    // K row (issue0); issue1 = kr+32
  const int kslot = (tid & 7) ^ (kr & 7);     // pre-swizzled K source 16B slot
  const int tp = tid & 127;
  const int vkey = 4 * (tp >> 3) + ((tp >> 1) & 3);       // V source key
  const int vcol = (tid >> 7) * 16 + (tid & 1) * 8;       // V source hd col (issue0)

  auto stage = [&](int kv, int c) {
    char* kb = smem + c * 8192;
    char* vb = smem + 16384 + c * 8192;
    GLOAD_LDS16(&Kp[(size_t)(kv + kr) * NHD + kslot * 8], kb + tid * 16);
    GLOAD_LDS16(&Kp[(size_t)(kv + kr + 32) * NHD + kslot * 8], kb + 4096 + tid * 16);
    GLOAD_LDS16(&Vp[(size_t)(kv + vkey) * NHD + vcol], vb + tid * 16);
    GLOAD_LDS16(&Vp[(size_t)(kv + vkey) * NHD + vcol + 32], vb + 4096 + tid * 16);
  };

  const int nt = 32 - pr;
  stage(0, 0);
  asm volatile("s_waitcnt vmcnt(0)" ::: "memory");
  __builtin_amdgcn_s_barrier();

  for (int t = 0; t < nt; t++) {
    const int cur = t & 1;
    const int kv0 = t * 64;
    if (t + 1 < nt) stage(kv0 + 64, cur ^ 1);  // prefetch next (hidden under compute)

    const f16* Kl = (const f16*)(smem + cur * 8192);
    const bool act0 = kv0 <= qb[0] + 15;  // sub1 always active

    // K fragments (A-operand): a[j] = K[key=ct*16+lo][hd=ks*32+8*hi+j]
    f16x8 kf[2][4];
#pragma unroll
    for (int ks = 0; ks < 2; ks++)
#pragma unroll
      for (int ct = 0; ct < 4; ct++) {
        int key = ct * 16 + lo;
        kf[ks][ct] = *(const f16x8*)&Kl[key * 64 + ((ks * 4 + hi) ^ (key & 7)) * 8];
      }

    f16x4 pb[2][4];  // P^T fragments -> PV B-operand
#pragma unroll
    for (int s = 0; s < 2; s++) {
      if (s == 0 && !act0) continue;
      f32x4 s_[4] = {};
#pragma unroll
      for (int ks = 0; ks < 2; ks++)
#pragma unroll
        for (int ct = 0; ct < 4; ct++)
          s_[ct] = MFMA32(kf[ks][ct], qf[s][ks], s_[ct]);

      if (kv0 + 63 > qb[s]) {  // diagonal: causal mask
        const int q = qb[s] + lo;
#pragma unroll
        for (int ct = 0; ct < 4; ct++)
#pragma unroll
          for (int r = 0; r < 4; r++)
            if (kv0 + ct * 16 + 4 * hi + r > q) s_[ct][r] = -3.0e38f;
      }
      float mt = -3.0e38f;
#pragma unroll
      for (int ct = 0; ct < 4; ct++)
        mt = fmaxf(mt, fmaxf(fmaxf(s_[ct][0], s_[ct][1]), fmaxf(s_[ct][2], s_[ct][3])));
      mt = fmaxf(mt, __shfl_xor(mt, 16));
      mt = fmaxf(mt, __shfl_xor(mt, 32));
      float mn = mreg[s];
      if (!__all(mt <= mn + 8.f)) {  // defer-max (T13)
        mn = fmaxf(mn, mt);
        const float al = exp2f(mreg[s] - mn);
        mreg[s] = mn;
        lsum[s] *= al;
#pragma unroll
        for (int ct = 0; ct < 4; ct++)
#pragma unroll
          for (int r = 0; r < 4; r++) oacc[s][ct][r] *= al;
      }
      float rs = 0.f;
#pragma unroll
      for (int ct = 0; ct < 4; ct++)
#pragma unroll
        for (int r = 0; r < 4; r++) {
          float p = exp2f(s_[ct][r] - mn);
          rs += p;
          pb[s][ct][r] = (f16)p;
        }
      rs += __shfl_xor(rs, 16);
      rs += __shfl_xor(rs, 32);
      lsum[s] += rs;
    }

    // PV: O^T += V^T P^T, V^T A-fragments via hardware transpose read
    lds_cp vtrb = (lds_cp)(smem + 16384 + cur * 8192) + lane * 8;
#pragma unroll
    for (int ct = 0; ct < 4; ct++) {
      lds_cp bct = vtrb + ct * 2048;
      f16x4 v0, v1, v2, v3;
      TR16(v0, bct, "0");
      TR16(v1, bct, "512");
      TR16(v2, bct, "1024");
      TR16(v3, bct, "1536");
      asm volatile("s_waitcnt lgkmcnt(0)" ::: "memory");
      __builtin_amdgcn_sched_barrier(0);
      if (act0) {
        oacc[0][ct] = MFMA16(v0, pb[0][0], oacc[0][ct]);
        oacc[0][ct] = MFMA16(v1, pb[0][1], oacc[0][ct]);
        oacc[0][ct] = MFMA16(v2, pb[0][2], oacc[0][ct]);
        oacc[0][ct] = MFMA16(v3, pb[0][3], oacc[0][ct]);
      }
      oacc[1][ct] = MFMA16(v0, pb[1][0], oacc[1][ct]);
      oacc[1][ct] = MFMA16(v1, pb[1][1], oacc[1][ct]);
      oacc[1][ct] = MFMA16(v2, pb[1][2], oacc[1][ct]);
      oacc[1][ct] = MFMA16(v3, pb[1][3], oacc[1][ct]);
    }

    asm volatile("s_waitcnt vmcnt(0)" ::: "memory");  // next tile staged (latency hidden)
    __builtin_amdgcn_s_barrier();
  }

  // epilogue: per sub, transpose via LDS then coalesced stores
#pragma unroll
  for (int s = 0; s < 2; s++) {
    __syncthreads();
    const float inv = 1.f / lsum[s];
#pragma unroll
    for (int ct = 0; ct < 4; ct++) {
      f16x4 o4;
#pragma unroll
      for (int r = 0; r < 4; r++) o4[r] = (f16)(oacc[s][ct][r] * inv);
      *(f16x4*)&Ol[w * 16 + lo][ct * 16 + 4 * hi] = o4;
    }
    __syncthreads();
#pragma unroll
    for (int i = 0; i < 2; i++) {
      int idx = tid + 256 * i;
      int qq = idx >> 3, ch = idx & 7;
      *(f16x8*)&y[((size_t)b * T + tile[s] * 64 + qq) * 1024 + (size_t)h * 64 + ch * 8] =
          *(const f16x8*)&Ol[qq][ch * 8];
    }
  }
}

extern "C" void kernel_launch(void* const* d_in, const int* in_sizes, int n_in,
                              void* d_out, int out_size, void* d_ws, size_t ws_size,
                              hipStream_t stream) {
  const float* x = (const float*)d_in[0];
  const float* w_qkv = (const float*)d_in[2];
  const float* w_proj = (const float*)d_in[3];

  constexpr int B = 4, T = 2048, C = 1024, NH = 16;
  constexpr int M = B * T;   // 8192
  constexpr int N1 = 3 * C;  // 3072

  char* ws = (char*)d_ws;
  f16* x16 = (f16*)ws;    ws += (size_t)M * C * 2;
  f16* wqkvT = (f16*)ws;  ws += (size_t)N1 * C * 2;
  f16* wprojT = (f16*)ws; ws += (size_t)C * C * 2;
  f16* qkvb = (f16*)ws;   ws += (size_t)M * N1 * 2;
  f16* y16 = (f16*)ws;

  cast_f32_f16_kernel<<<(M * C / 4 + 255) / 256, 256, 0, stream>>>(x, x16, M * C / 4);
  transpose_cast_kernel<<<dim3(N1 / 32, C / 32), 256, 0, stream>>>(w_qkv, wqkvT, C, N1);
  transpose_cast_kernel<<<dim3(C / 32, C / 32), 256, 0, stream>>>(w_proj, wprojT, C, C);
  gemm_f16_kernel<false><<<dim3(N1 / 128, M / 128), 256, 0, stream>>>(x16, wqkvT, qkvb, M, N1, C);
  attn_kernel<<<dim3(B * NH, 16), 256, 0, stream>>>(qkvb, y16);
  gemm_f16_kernel<true><<<dim3(C / 128, M / 128), 256, 0, stream>>>(y16, wprojT, (float*)d_out, M, C, C);
}

// Round 5
// 186.972 us; speedup vs baseline: 2.3770x; 1.0876x over previous
//
#include <hip/hip_runtime.h>
#include <hip/hip_bf16.h>

typedef _Float16 f16;
typedef __attribute__((ext_vector_type(4))) _Float16 f16x4;
typedef __attribute__((ext_vector_type(8))) _Float16 f16x8;
typedef __attribute__((ext_vector_type(4))) float f32x4;

#define MFMA16(a, b, c) __builtin_amdgcn_mfma_f32_16x16x16f16((a), (b), (c), 0, 0, 0)
#define MFMA32(a, b, c) __builtin_amdgcn_mfma_f32_16x16x32_f16((a), (b), (c), 0, 0, 0)
#define EXP2(x) __builtin_amdgcn_exp2f(x)
#define GLOAD_LDS16(g, l)                                                        \
  __builtin_amdgcn_global_load_lds((const __attribute__((address_space(1))) void*)(g), \
                                   (__attribute__((address_space(3))) void*)(l), 16, 0, 0)
typedef const __attribute__((address_space(3))) char* lds_cp;
#define TR16(dst, addr, imm) \
  asm volatile("ds_read_b64_tr_b16 %0, %1 offset:" imm : "=v"(dst) : "v"(addr))

// ---------------- cast fp32 -> fp16 (vectorized) ----------------
__global__ __launch_bounds__(256) void cast_f32_f16_kernel(
    const float* __restrict__ in, f16* __restrict__ out, int n4) {
  int i = blockIdx.x * 256 + threadIdx.x;
  if (i >= n4) return;
  const float4 v = reinterpret_cast<const float4*>(in)[i];
  f16x4 h;
  h[0] = (f16)v.x; h[1] = (f16)v.y; h[2] = (f16)v.z; h[3] = (f16)v.w;
  reinterpret_cast<f16x4*>(out)[i] = h;
}

// ------------- transpose + cast: src[R][Cc] f32 -> dst[Cc][R] f16 -------------
__global__ __launch_bounds__(256) void transpose_cast_kernel(
    const float* __restrict__ src, f16* __restrict__ dst, int R, int Cc) {
  __shared__ float t[32][33];
  int tx0 = blockIdx.x * 32, ty0 = blockIdx.y * 32;
  int c = threadIdx.x & 31;
  int r0 = threadIdx.x >> 5;
#pragma unroll
  for (int i = 0; i < 4; i++) {
    int r = r0 + 8 * i;
    t[r][c] = src[(size_t)(ty0 + r) * Cc + tx0 + c];
  }
  __syncthreads();
#pragma unroll
  for (int i = 0; i < 4; i++) {
    int a = r0 + 8 * i;
    dst[(size_t)(tx0 + a) * R + ty0 + c] = (f16)t[c][a];
  }
}

// ---------------- GEMM: 2-phase prefetch dbuf; C[M][N] = A[M][K] * Bt[N][K]^T ----------------
// 128x128 tile, 4 waves (2x2), 16x16x32 MFMA, BK=32, double-buffered LDS,
// global_load_lds w16 issued for tile t+1 BEFORE computing tile t (T3-minimum).
template <bool OUT_F32>
__global__ __launch_bounds__(256) void gemm_f16_kernel(
    const f16* __restrict__ A, const f16* __restrict__ Bt, void* __restrict__ Cout,
    int M, int N, int K) {
  constexpr int BK = 32;
  __shared__ f16 Al[2][128 * BK];
  __shared__ f16 Bl[2][128 * BK];

  const int tid = threadIdx.x;
  const int lane = tid & 63, wid = tid >> 6;
  const int wm = wid >> 1, wn = wid & 1;
  const int lo = lane & 15, hi = lane >> 4;
  const int tn0 = blockIdx.x * 128, tm0 = blockIdx.y * 128;

  f32x4 acc[4][4] = {};

  const int r1 = tid >> 2, o1 = (tid & 3) * 8;  // rows 0..63 (+64 for second issue)

  auto stage = [&](int kt, int c) {
    GLOAD_LDS16(&A[(size_t)(tm0 + r1) * K + kt + o1], &Al[c][tid * 8]);
    GLOAD_LDS16(&A[(size_t)(tm0 + r1 + 64) * K + kt + o1], &Al[c][(tid + 256) * 8]);
    GLOAD_LDS16(&Bt[(size_t)(tn0 + r1) * K + kt + o1], &Bl[c][tid * 8]);
    GLOAD_LDS16(&Bt[(size_t)(tn0 + r1 + 64) * K + kt + o1], &Bl[c][(tid + 256) * 8]);
  };

  stage(0, 0);
  asm volatile("s_waitcnt vmcnt(0)" ::: "memory");
  __builtin_amdgcn_s_barrier();

  for (int kt = 0; kt < K; kt += BK) {
    const int cur = (kt >> 5) & 1;
    if (kt + BK < K) stage(kt + BK, cur ^ 1);  // prefetch hides under MFMA

    f16x8 af[4], bf[4];
#pragma unroll
    for (int mi = 0; mi < 4; mi++)
      af[mi] = *(const f16x8*)&Al[cur][(wm * 64 + mi * 16 + lo) * BK + 8 * hi];
#pragma unroll
    for (int ni = 0; ni < 4; ni++)
      bf[ni] = *(const f16x8*)&Bl[cur][(wn * 64 + ni * 16 + lo) * BK + 8 * hi];
#pragma unroll
    for (int mi = 0; mi < 4; mi++)
#pragma unroll
      for (int ni = 0; ni < 4; ni++)
        acc[mi][ni] = MFMA32(af[mi], bf[ni], acc[mi][ni]);

    asm volatile("s_waitcnt vmcnt(0)" ::: "memory");  // next tile landed
    __builtin_amdgcn_s_barrier();
  }

#pragma unroll
  for (int mi = 0; mi < 4; mi++)
#pragma unroll
    for (int ni = 0; ni < 4; ni++)
#pragma unroll
      for (int r = 0; r < 4; r++) {
        int row = tm0 + wm * 64 + mi * 16 + 4 * hi + r;
        int col = tn0 + wn * 64 + ni * 16 + lo;
        float v = acc[mi][ni][r];
        if (OUT_F32)
          ((float*)Cout)[(size_t)row * N + col] = v;
        else
          ((f16*)Cout)[(size_t)row * N + col] = (f16)v;
      }
}

// ---------------- causal flash attention ----------------
// Paired q-tiles {p, 31-p}; double-buffered K/V; V blocked for ds_read_b64_tr_b16;
// raw v_exp_f32 softmax; setprio around MFMA clusters.
__global__ __launch_bounds__(256, 4) void attn_kernel(
    const f16* __restrict__ qkv, f16* __restrict__ y) {
  constexpr int T = 2048, NHD = 3072, LDO = 72;
  const int bh = blockIdx.x;
  const int b = bh >> 4, h = bh & 15;
  const int pr = blockIdx.y;  // pair index 0..15
  const int tid = threadIdx.x;
  const int lane = tid & 63, w = tid >> 6;
  const int lo = lane & 15, hi = lane >> 4;

  const size_t base = (size_t)b * T * NHD + (size_t)h * 64;
  const f16* Qp = qkv + base;
  const f16* Kp = qkv + base + 1024;
  const f16* Vp = qkv + base + 2048;

  // [K0 8K][K1 8K][V0 8K][V1 8K]; epilogue Ol aliases the front.
  __shared__ __align__(16) char smem[32768];
  f16 (*Ol)[LDO] = (f16(*)[LDO])smem;

  const int tile[2] = {pr, 31 - pr};
  const int qb[2] = {tile[0] * 64 + w * 16, tile[1] * 64 + w * 16};

  // Q fragments pre-scaled by 1/sqrt(64)*log2(e)
  const float scf = 0.125f * 1.44269504089f;
  f16x8 qf[2][2];
#pragma unroll
  for (int s = 0; s < 2; s++) {
    const f16* qrow = Qp + (size_t)(qb[s] + lo) * NHD;
#pragma unroll
    for (int ks = 0; ks < 2; ks++) {
      f16x8 v = *(const f16x8*)&qrow[ks * 32 + 8 * hi];
#pragma unroll
      for (int j = 0; j < 8; j++) v[j] = (f16)((float)v[j] * scf);
      qf[s][ks] = v;
    }
  }

  f32x4 oacc[2][4] = {};  // O^T[hd=ct*16+4hi+r][q=lo]
  float mreg[2] = {-1e30f, -1e30f};
  float lsum[2] = {0.f, 0.f};

  // staging coords
  const int kr = tid >> 3;                    // K row (issue0); issue1 = kr+32
  const int kslot = (tid & 7) ^ (kr & 7);     // pre-swizzled K source 16B slot
  const int tp = tid & 127;
  const int vkey = 4 * (tp >> 3) + ((tp >> 1) & 3);       // V source key
  const int vcol = (tid >> 7) * 16 + (tid & 1) * 8;       // V source hd col

  // K-fragment LDS element offsets (lane-constant; ct folds into imm offset)
  const int kfo0 = lo * 64 + ((hi ^ (lo & 7)) * 8);
  const int kfo1 = lo * 64 + (((4 + hi) ^ (lo & 7)) * 8);

  auto stage = [&](int kv, int c) {
    char* kb = smem + c * 8192;
    char* vb = smem + 16384 + c * 8192;
    GLOAD_LDS16(&Kp[(size_t)(kv + kr) * NHD + kslot * 8], kb + tid * 16);
    GLOAD_LDS16(&Kp[(size_t)(kv + kr + 32) * NHD + kslot * 8], kb + 4096 + tid * 16);
    GLOAD_LDS16(&Vp[(size_t)(kv + vkey) * NHD + vcol], vb + tid * 16);
    GLOAD_LDS16(&Vp[(size_t)(kv + vkey) * NHD + vcol + 32], vb + 4096 + tid * 16);
  };

  const int nt = 32 - pr;
  stage(0, 0);
  asm volatile("s_waitcnt vmcnt(0)" ::: "memory");
  __builtin_amdgcn_s_barrier();

  for (int t = 0; t < nt; t++) {
    const int cur = t & 1;
    const int kv0 = t * 64;
    if (t + 1 < nt) stage(kv0 + 64, cur ^ 1);  // prefetch next

    const f16* Kl = (const f16*)(smem + cur * 8192);
    const bool act0 = kv0 <= qb[0] + 15;  // sub1 always active

    // K fragments: a[j] = K[key=ct*16+lo][hd=ks*32+8*hi+j] (swizzled, imm offsets)
    f16x8 kf[2][4];
#pragma unroll
    for (int ct = 0; ct < 4; ct++) {
      kf[0][ct] = *(const f16x8*)&Kl[ct * 1024 + kfo0];
      kf[1][ct] = *(const f16x8*)&Kl[ct * 1024 + kfo1];
    }

    f16x4 pb[2][4];  // P^T fragments -> PV B-operand
#pragma unroll
    for (int s = 0; s < 2; s++) {
      if (s == 0 && !act0) continue;
      f32x4 s_[4] = {};
      __builtin_amdgcn_s_setprio(1);
#pragma unroll
      for (int ks = 0; ks < 2; ks++)
#pragma unroll
        for (int ct = 0; ct < 4; ct++)
          s_[ct] = MFMA32(kf[ks][ct], qf[s][ks], s_[ct]);
      __builtin_amdgcn_s_setprio(0);

      if (kv0 + 63 > qb[s]) {  // diagonal: causal mask
        const int q = qb[s] + lo;
#pragma unroll
        for (int ct = 0; ct < 4; ct++)
#pragma unroll
          for (int r = 0; r < 4; r++)
            if (kv0 + ct * 16 + 4 * hi + r > q) s_[ct][r] = -3.0e38f;
      }
      float mt = -3.0e38f;
#pragma unroll
      for (int ct = 0; ct < 4; ct++)
        mt = fmaxf(mt, fmaxf(fmaxf(s_[ct][0], s_[ct][1]), fmaxf(s_[ct][2], s_[ct][3])));
      mt = fmaxf(mt, __shfl_xor(mt, 16));
      mt = fmaxf(mt, __shfl_xor(mt, 32));
      float mn = mreg[s];
      if (!__all(mt <= mn + 8.f)) {  // defer-max (T13)
        mn = fmaxf(mn, mt);
        const float al = EXP2(mreg[s] - mn);
        mreg[s] = mn;
        lsum[s] *= al;
#pragma unroll
        for (int ct = 0; ct < 4; ct++)
#pragma unroll
          for (int r = 0; r < 4; r++) oacc[s][ct][r] *= al;
      }
      float rs = 0.f;
#pragma unroll
      for (int ct = 0; ct < 4; ct++)
#pragma unroll
        for (int r = 0; r < 4; r++) {
          float p = EXP2(s_[ct][r] - mn);
          rs += p;
          pb[s][ct][r] = (f16)p;
        }
      rs += __shfl_xor(rs, 16);
      rs += __shfl_xor(rs, 32);
      lsum[s] += rs;
    }

    // PV: O^T += V^T P^T, V^T A-fragments via hardware transpose read
    lds_cp vtrb = (lds_cp)(smem + 16384 + cur * 8192) + lane * 8;
#pragma unroll
    for (int ct = 0; ct < 4; ct++) {
      lds_cp bct = vtrb + ct * 2048;
      f16x4 v0, v1, v2, v3;
      TR16(v0, bct, "0");
      TR16(v1, bct, "512");
      TR16(v2, bct, "1024");
      TR16(v3, bct, "1536");
      asm volatile("s_waitcnt lgkmcnt(0)" ::: "memory");
      __builtin_amdgcn_sched_barrier(0);
      __builtin_amdgcn_s_setprio(1);
      if (act0) {
        oacc[0][ct] = MFMA16(v0, pb[0][0], oacc[0][ct]);
        oacc[0][ct] = MFMA16(v1, pb[0][1], oacc[0][ct]);
        oacc[0][ct] = MFMA16(v2, pb[0][2], oacc[0][ct]);
        oacc[0][ct] = MFMA16(v3, pb[0][3], oacc[0][ct]);
      }
      oacc[1][ct] = MFMA16(v0, pb[1][0], oacc[1][ct]);
      oacc[1][ct] = MFMA16(v1, pb[1][1], oacc[1][ct]);
      oacc[1][ct] = MFMA16(v2, pb[1][2], oacc[1][ct]);
      oacc[1][ct] = MFMA16(v3, pb[1][3], oacc[1][ct]);
      __builtin_amdgcn_s_setprio(0);
    }

    asm volatile("s_waitcnt vmcnt(0)" ::: "memory");  // next tile staged
    __builtin_amdgcn_s_barrier();
  }

  // epilogue: per sub, transpose via LDS then coalesced stores
#pragma unroll
  for (int s = 0; s < 2; s++) {
    __syncthreads();
    const float inv = 1.f / lsum[s];
#pragma unroll
    for (int ct = 0; ct < 4; ct++) {
      f16x4 o4;
#pragma unroll
      for (int r = 0; r < 4; r++) o4[r] = (f16)(oacc[s][ct][r] * inv);
      *(f16x4*)&Ol[w * 16 + lo][ct * 16 + 4 * hi] = o4;
    }
    __syncthreads();
#pragma unroll
    for (int i = 0; i < 2; i++) {
      int idx = tid + 256 * i;
      int qq = idx >> 3, ch = idx & 7;
      *(f16x8*)&y[((size_t)b * T + tile[s] * 64 + qq) * 1024 + (size_t)h * 64 + ch * 8] =
          *(const f16x8*)&Ol[qq][ch * 8];
    }
  }
}

extern "C" void kernel_launch(void* const* d_in, const int* in_sizes, int n_in,
                              void* d_out, int out_size, void* d_ws, size_t ws_size,
                              hipStream_t stream) {
  const float* x = (const float*)d_in[0];
  const float* w_qkv = (const float*)d_in[2];
  const float* w_proj = (const float*)d_in[3];

  constexpr int B = 4, T = 2048, C = 1024, NH = 16;
  constexpr int M = B * T;   // 8192
  constexpr int N1 = 3 * C;  // 3072

  char* ws = (char*)d_ws;
  f16* x16 = (f16*)ws;    ws += (size_t)M * C * 2;
  f16* wqkvT = (f16*)ws;  ws += (size_t)N1 * C * 2;
  f16* wprojT = (f16*)ws; ws += (size_t)C * C * 2;
  f16* qkvb = (f16*)ws;   ws += (size_t)M * N1 * 2;
  f16* y16 = (f16*)ws;

  cast_f32_f16_kernel<<<(M * C / 4 + 255) / 256, 256, 0, stream>>>(x, x16, M * C / 4);
  transpose_cast_kernel<<<dim3(N1 / 32, C / 32), 256, 0, stream>>>(w_qkv, wqkvT, C, N1);
  transpose_cast_kernel<<<dim3(C / 32, C / 32), 256, 0, stream>>>(w_proj, wprojT, C, C);
  gemm_f16_kernel<false><<<dim3(N1 / 128, M / 128), 256, 0, stream>>>(x16, wqkvT, qkvb, M, N1, C);
  attn_kernel<<<dim3(B * NH, 16), 256, 0, stream>>>(qkvb, y16);
  gemm_f16_kernel<true><<<dim3(C / 128, M / 128), 256, 0, stream>>>(y16, wprojT, (float*)d_out, M, C, C);
}

// Round 6
// 179.696 us; speedup vs baseline: 2.4732x; 1.0405x over previous
//
#include <hip/hip_runtime.h>
#include <hip/hip_bf16.h>

typedef _Float16 f16;
typedef __attribute__((ext_vector_type(4))) _Float16 f16x4;
typedef __attribute__((ext_vector_type(8))) _Float16 f16x8;
typedef __attribute__((ext_vector_type(4))) float f32x4;

#define MFMA16(a, b, c) __builtin_amdgcn_mfma_f32_16x16x16f16((a), (b), (c), 0, 0, 0)
#define MFMA32(a, b, c) __builtin_amdgcn_mfma_f32_16x16x32_f16((a), (b), (c), 0, 0, 0)
#define EXP2(x) __builtin_amdgcn_exp2f(x)
#define GLOAD_LDS16(g, l)                                                        \
  __builtin_amdgcn_global_load_lds((const __attribute__((address_space(1))) void*)(g), \
                                   (__attribute__((address_space(3))) void*)(l), 16, 0, 0)
typedef const __attribute__((address_space(3))) char* lds_cp;
#define TR16(dst, addr, imm) \
  asm volatile("ds_read_b64_tr_b16 %0, %1 offset:" imm : "=v"(dst) : "v"(addr))

// ---------------- cast fp32 -> fp16 (vectorized) ----------------
__global__ __launch_bounds__(256) void cast_f32_f16_kernel(
    const float* __restrict__ in, f16* __restrict__ out, int n4) {
  int i = blockIdx.x * 256 + threadIdx.x;
  if (i >= n4) return;
  const float4 v = reinterpret_cast<const float4*>(in)[i];
  f16x4 h;
  h[0] = (f16)v.x; h[1] = (f16)v.y; h[2] = (f16)v.z; h[3] = (f16)v.w;
  reinterpret_cast<f16x4*>(out)[i] = h;
}

// ------------- transpose + cast: src[R][Cc] f32 -> dst[Cc][R] f16 -------------
__global__ __launch_bounds__(256) void transpose_cast_kernel(
    const float* __restrict__ src, f16* __restrict__ dst, int R, int Cc) {
  __shared__ float t[32][33];
  int tx0 = blockIdx.x * 32, ty0 = blockIdx.y * 32;
  int c = threadIdx.x & 31;
  int r0 = threadIdx.x >> 5;
#pragma unroll
  for (int i = 0; i < 4; i++) {
    int r = r0 + 8 * i;
    t[r][c] = src[(size_t)(ty0 + r) * Cc + tx0 + c];
  }
  __syncthreads();
#pragma unroll
  for (int i = 0; i < 4; i++) {
    int a = r0 + 8 * i;
    dst[(size_t)(tx0 + a) * R + ty0 + c] = (f16)t[c][a];
  }
}

// ---------------- GEMM: triple-buffered, counted vmcnt (T4) ----------------
// 128x128 tile, 4 waves (2x2), 16x16x32 MFMA, BK=32.
// Iter t: vmcnt(4) [tile t landed, t+1 in flight] -> barrier -> stage(t+2) ->
// ds_read + MFMA. Loads never drained to 0 in the loop (AITER pattern).
template <bool OUT_F32>
__global__ __launch_bounds__(256) void gemm_f16_kernel(
    const f16* __restrict__ A, const f16* __restrict__ Bt, void* __restrict__ Cout,
    int M, int N, int K) {
  constexpr int BK = 32;
  __shared__ f16 Al[3][128 * BK];
  __shared__ f16 Bl[3][128 * BK];

  const int tid = threadIdx.x;
  const int lane = tid & 63, wid = tid >> 6;
  const int wm = wid >> 1, wn = wid & 1;
  const int lo = lane & 15, hi = lane >> 4;
  const int tn0 = blockIdx.x * 128, tm0 = blockIdx.y * 128;

  f32x4 acc[4][4] = {};

  const int r1 = tid >> 2, o1 = (tid & 3) * 8;  // rows 0..63 (+64 for second issue)

  auto stage = [&](int kt, int c) {
    GLOAD_LDS16(&A[(size_t)(tm0 + r1) * K + kt + o1], &Al[c][tid * 8]);
    GLOAD_LDS16(&A[(size_t)(tm0 + r1 + 64) * K + kt + o1], &Al[c][(tid + 256) * 8]);
    GLOAD_LDS16(&Bt[(size_t)(tn0 + r1) * K + kt + o1], &Bl[c][tid * 8]);
    GLOAD_LDS16(&Bt[(size_t)(tn0 + r1 + 64) * K + kt + o1], &Bl[c][(tid + 256) * 8]);
  };

  auto compute = [&](int cur) {
    f16x8 af[4], bf[4];
#pragma unroll
    for (int mi = 0; mi < 4; mi++)
      af[mi] = *(const f16x8*)&Al[cur][(wm * 64 + mi * 16 + lo) * BK + 8 * hi];
#pragma unroll
    for (int ni = 0; ni < 4; ni++)
      bf[ni] = *(const f16x8*)&Bl[cur][(wn * 64 + ni * 16 + lo) * BK + 8 * hi];
    __builtin_amdgcn_s_setprio(1);
#pragma unroll
    for (int mi = 0; mi < 4; mi++)
#pragma unroll
      for (int ni = 0; ni < 4; ni++)
        acc[mi][ni] = MFMA32(af[mi], bf[ni], acc[mi][ni]);
    __builtin_amdgcn_s_setprio(0);
  };

  const int NT = K / BK;
  stage(0, 0);
  stage(BK, 1);

  int cur = 0;
  for (int t = 0; t < NT - 1; t++) {
    asm volatile("s_waitcnt vmcnt(4)" ::: "memory");  // tile t landed; t+1 in flight
    __builtin_amdgcn_s_barrier();                     // buf[(t+2)%3] readers done
    if (t + 2 < NT) stage((t + 2) * BK, (t + 2) % 3);
    compute(cur);
    cur = (cur == 2) ? 0 : cur + 1;
  }
  asm volatile("s_waitcnt vmcnt(0)" ::: "memory");    // final tile
  __builtin_amdgcn_s_barrier();
  compute(cur);

#pragma unroll
  for (int mi = 0; mi < 4; mi++)
#pragma unroll
    for (int ni = 0; ni < 4; ni++)
#pragma unroll
      for (int r = 0; r < 4; r++) {
        int row = tm0 + wm * 64 + mi * 16 + 4 * hi + r;
        int col = tn0 + wn * 64 + ni * 16 + lo;
        float v = acc[mi][ni][r];
        if (OUT_F32)
          ((float*)Cout)[(size_t)row * N + col] = v;
        else
          ((f16*)Cout)[(size_t)row * N + col] = (f16)v;
      }
}

// ---------------- causal flash attention ----------------
// Paired q-tiles {p, 31-p}; double-buffered K/V; V blocked for ds_read_b64_tr_b16;
// raw v_exp_f32 softmax; setprio around MFMA clusters.
__global__ __launch_bounds__(256, 4) void attn_kernel(
    const f16* __restrict__ qkv, f16* __restrict__ y) {
  constexpr int T = 2048, NHD = 3072, LDO = 72;
  const int bh = blockIdx.x;
  const int b = bh >> 4, h = bh & 15;
  const int pr = blockIdx.y;  // pair index 0..15
  const int tid = threadIdx.x;
  const int lane = tid & 63, w = tid >> 6;
  const int lo = lane & 15, hi = lane >> 4;

  const size_t base = (size_t)b * T * NHD + (size_t)h * 64;
  const f16* Qp = qkv + base;
  const f16* Kp = qkv + base + 1024;
  const f16* Vp = qkv + base + 2048;

  // [K0 8K][K1 8K][V0 8K][V1 8K]; epilogue Ol aliases the front.
  __shared__ __align__(16) char smem[32768];
  f16 (*Ol)[LDO] = (f16(*)[LDO])smem;

  const int tile[2] = {pr, 31 - pr};
  const int qb[2] = {tile[0] * 64 + w * 16, tile[1] * 64 + w * 16};

  // Q fragments pre-scaled by 1/sqrt(64)*log2(e)
  const float scf = 0.125f * 1.44269504089f;
  f16x8 qf[2][2];
#pragma unroll
  for (int s = 0; s < 2; s++) {
    const f16* qrow = Qp + (size_t)(qb[s] + lo) * NHD;
#pragma unroll
    for (int ks = 0; ks < 2; ks++) {
      f16x8 v = *(const f16x8*)&qrow[ks * 32 + 8 * hi];
#pragma unroll
      for (int j = 0; j < 8; j++) v[j] = (f16)((float)v[j] * scf);
      qf[s][ks] = v;
    }
  }

  f32x4 oacc[2][4] = {};  // O^T[hd=ct*16+4hi+r][q=lo]
  float mreg[2] = {-1e30f, -1e30f};
  float lsum[2] = {0.f, 0.f};

  // staging coords
  const int kr = tid >> 3;                    // K row (issue0); issue1 = kr+32
  const int kslot = (tid & 7) ^ (kr & 7);     // pre-swizzled K source 16B slot
  const int tp = tid & 127;
  const int vkey = 4 * (tp >> 3) + ((tp >> 1) & 3);       // V source key
  const int vcol = (tid >> 7) * 16 + (tid & 1) * 8;       // V source hd col

  // K-fragment LDS element offsets (lane-constant; ct folds into imm offset)
  const int kfo0 = lo * 64 + ((hi ^ (lo & 7)) * 8);
  const int kfo1 = lo * 64 + (((4 + hi) ^ (lo & 7)) * 8);

  auto stage = [&](int kv, int c) {
    char* kb = smem + c * 8192;
    char* vb = smem + 16384 + c * 8192;
    GLOAD_LDS16(&Kp[(size_t)(kv + kr) * NHD + kslot * 8], kb + tid * 16);
    GLOAD_LDS16(&Kp[(size_t)(kv + kr + 32) * NHD + kslot * 8], kb + 4096 + tid * 16);
    GLOAD_LDS16(&Vp[(size_t)(kv + vkey) * NHD + vcol], vb + tid * 16);
    GLOAD_LDS16(&Vp[(size_t)(kv + vkey) * NHD + vcol + 32], vb + 4096 + tid * 16);
  };

  const int nt = 32 - pr;
  stage(0, 0);
  asm volatile("s_waitcnt vmcnt(0)" ::: "memory");
  __builtin_amdgcn_s_barrier();

  for (int t = 0; t < nt; t++) {
    const int cur = t & 1;
    const int kv0 = t * 64;
    if (t + 1 < nt) stage(kv0 + 64, cur ^ 1);  // prefetch next

    const f16* Kl = (const f16*)(smem + cur * 8192);
    const bool act0 = kv0 <= qb[0] + 15;  // sub1 always active

    // K fragments: a[j] = K[key=ct*16+lo][hd=ks*32+8*hi+j] (swizzled, imm offsets)
    f16x8 kf[2][4];
#pragma unroll
    for (int ct = 0; ct < 4; ct++) {
      kf[0][ct] = *(const f16x8*)&Kl[ct * 1024 + kfo0];
      kf[1][ct] = *(const f16x8*)&Kl[ct * 1024 + kfo1];
    }

    f16x4 pb[2][4];  // P^T fragments -> PV B-operand
#pragma unroll
    for (int s = 0; s < 2; s++) {
      if (s == 0 && !act0) continue;
      f32x4 s_[4] = {};
      __builtin_amdgcn_s_setprio(1);
#pragma unroll
      for (int ks = 0; ks < 2; ks++)
#pragma unroll
        for (int ct = 0; ct < 4; ct++)
          s_[ct] = MFMA32(kf[ks][ct], qf[s][ks], s_[ct]);
      __builtin_amdgcn_s_setprio(0);

      if (kv0 + 63 > qb[s]) {  // diagonal: causal mask
        const int q = qb[s] + lo;
#pragma unroll
        for (int ct = 0; ct < 4; ct++)
#pragma unroll
          for (int r = 0; r < 4; r++)
            if (kv0 + ct * 16 + 4 * hi + r > q) s_[ct][r] = -3.0e38f;
      }
      float mt = -3.0e38f;
#pragma unroll
      for (int ct = 0; ct < 4; ct++)
        mt = fmaxf(mt, fmaxf(fmaxf(s_[ct][0], s_[ct][1]), fmaxf(s_[ct][2], s_[ct][3])));
      mt = fmaxf(mt, __shfl_xor(mt, 16));
      mt = fmaxf(mt, __shfl_xor(mt, 32));
      float mn = mreg[s];
      if (!__all(mt <= mn + 8.f)) {  // defer-max (T13)
        mn = fmaxf(mn, mt);
        const float al = EXP2(mreg[s] - mn);
        mreg[s] = mn;
        lsum[s] *= al;
#pragma unroll
        for (int ct = 0; ct < 4; ct++)
#pragma unroll
          for (int r = 0; r < 4; r++) oacc[s][ct][r] *= al;
      }
      float rs = 0.f;
#pragma unroll
      for (int ct = 0; ct < 4; ct++)
#pragma unroll
        for (int r = 0; r < 4; r++) {
          float p = EXP2(s_[ct][r] - mn);
          rs += p;
          pb[s][ct][r] = (f16)p;
        }
      rs += __shfl_xor(rs, 16);
      rs += __shfl_xor(rs, 32);
      lsum[s] += rs;
    }

    // PV: O^T += V^T P^T, V^T A-fragments via hardware transpose read
    lds_cp vtrb = (lds_cp)(smem + 16384 + cur * 8192) + lane * 8;
#pragma unroll
    for (int ct = 0; ct < 4; ct++) {
      lds_cp bct = vtrb + ct * 2048;
      f16x4 v0, v1, v2, v3;
      TR16(v0, bct, "0");
      TR16(v1, bct, "512");
      TR16(v2, bct, "1024");
      TR16(v3, bct, "1536");
      asm volatile("s_waitcnt lgkmcnt(0)" ::: "memory");
      __builtin_amdgcn_sched_barrier(0);
      __builtin_amdgcn_s_setprio(1);
      if (act0) {
        oacc[0][ct] = MFMA16(v0, pb[0][0], oacc[0][ct]);
        oacc[0][ct] = MFMA16(v1, pb[0][1], oacc[0][ct]);
        oacc[0][ct] = MFMA16(v2, pb[0][2], oacc[0][ct]);
        oacc[0][ct] = MFMA16(v3, pb[0][3], oacc[0][ct]);
      }
      oacc[1][ct] = MFMA16(v0, pb[1][0], oacc[1][ct]);
      oacc[1][ct] = MFMA16(v1, pb[1][1], oacc[1][ct]);
      oacc[1][ct] = MFMA16(v2, pb[1][2], oacc[1][ct]);
      oacc[1][ct] = MFMA16(v3, pb[1][3], oacc[1][ct]);
      __builtin_amdgcn_s_setprio(0);
    }

    asm volatile("s_waitcnt vmcnt(0)" ::: "memory");  // next tile staged
    __builtin_amdgcn_s_barrier();
  }

  // epilogue: per sub, transpose via LDS then coalesced stores
#pragma unroll
  for (int s = 0; s < 2; s++) {
    __syncthreads();
    const float inv = 1.f / lsum[s];
#pragma unroll
    for (int ct = 0; ct < 4; ct++) {
      f16x4 o4;
#pragma unroll
      for (int r = 0; r < 4; r++) o4[r] = (f16)(oacc[s][ct][r] * inv);
      *(f16x4*)&Ol[w * 16 + lo][ct * 16 + 4 * hi] = o4;
    }
    __syncthreads();
#pragma unroll
    for (int i = 0; i < 2; i++) {
      int idx = tid + 256 * i;
      int qq = idx >> 3, ch = idx & 7;
      *(f16x8*)&y[((size_t)b * T + tile[s] * 64 + qq) * 1024 + (size_t)h * 64 + ch * 8] =
          *(const f16x8*)&Ol[qq][ch * 8];
    }
  }
}

extern "C" void kernel_launch(void* const* d_in, const int* in_sizes, int n_in,
                              void* d_out, int out_size, void* d_ws, size_t ws_size,
                              hipStream_t stream) {
  const float* x = (const float*)d_in[0];
  const float* w_qkv = (const float*)d_in[2];
  const float* w_proj = (const float*)d_in[3];

  constexpr int B = 4, T = 2048, C = 1024, NH = 16;
  constexpr int M = B * T;   // 8192
  constexpr int N1 = 3 * C;  // 3072

  char* ws = (char*)d_ws;
  f16* x16 = (f16*)ws;    ws += (size_t)M * C * 2;
  f16* wqkvT = (f16*)ws;  ws += (size_t)N1 * C * 2;
  f16* wprojT = (f16*)ws; ws += (size_t)C * C * 2;
  f16* qkvb = (f16*)ws;   ws += (size_t)M * N1 * 2;
  f16* y16 = (f16*)ws;

  cast_f32_f16_kernel<<<(M * C / 4 + 255) / 256, 256, 0, stream>>>(x, x16, M * C / 4);
  transpose_cast_kernel<<<dim3(N1 / 32, C / 32), 256, 0, stream>>>(w_qkv, wqkvT, C, N1);
  transpose_cast_kernel<<<dim3(C / 32, C / 32), 256, 0, stream>>>(w_proj, wprojT, C, C);
  gemm_f16_kernel<false><<<dim3(N1 / 128, M / 128), 256, 0, stream>>>(x16, wqkvT, qkvb, M, N1, C);
  attn_kernel<<<dim3(B * NH, 16), 256, 0, stream>>>(qkvb, y16);
  gemm_f16_kernel<true><<<dim3(C / 128, M / 128), 256, 0, stream>>>(y16, wprojT, (float*)d_out, M, C, C);
}

// Round 7
// 175.820 us; speedup vs baseline: 2.5277x; 1.0220x over previous
//
#include <hip/hip_runtime.h>
#include <hip/hip_bf16.h>

typedef _Float16 f16;
typedef __attribute__((ext_vector_type(4))) _Float16 f16x4;
typedef __attribute__((ext_vector_type(8))) _Float16 f16x8;
typedef __attribute__((ext_vector_type(4))) float f32x4;

#define MFMA16(a, b, c) __builtin_amdgcn_mfma_f32_16x16x16f16((a), (b), (c), 0, 0, 0)
#define MFMA32(a, b, c) __builtin_amdgcn_mfma_f32_16x16x32_f16((a), (b), (c), 0, 0, 0)
#define EXP2(x) __builtin_amdgcn_exp2f(x)
#define GLOAD_LDS16(g, l)                                                        \
  __builtin_amdgcn_global_load_lds((const __attribute__((address_space(1))) void*)(g), \
                                   (__attribute__((address_space(3))) void*)(l), 16, 0, 0)
typedef const __attribute__((address_space(3))) char* lds_cp;
#define TR16(dst, addr, imm) \
  asm volatile("ds_read_b64_tr_b16 %0, %1 offset:" imm : "=v"(dst) : "v"(addr))

// ---------------- cast fp32 -> fp16 (vectorized) ----------------
__global__ __launch_bounds__(256) void cast_f32_f16_kernel(
    const float* __restrict__ in, f16* __restrict__ out, int n4) {
  int i = blockIdx.x * 256 + threadIdx.x;
  if (i >= n4) return;
  const float4 v = reinterpret_cast<const float4*>(in)[i];
  f16x4 h;
  h[0] = (f16)v.x; h[1] = (f16)v.y; h[2] = (f16)v.z; h[3] = (f16)v.w;
  reinterpret_cast<f16x4*>(out)[i] = h;
}

// ------------- transpose + cast: src[R][Cc] f32 -> dst[Cc][R] f16 -------------
__global__ __launch_bounds__(256) void transpose_cast_kernel(
    const float* __restrict__ src, f16* __restrict__ dst, int R, int Cc) {
  __shared__ float t[32][33];
  int tx0 = blockIdx.x * 32, ty0 = blockIdx.y * 32;
  int c = threadIdx.x & 31;
  int r0 = threadIdx.x >> 5;
#pragma unroll
  for (int i = 0; i < 4; i++) {
    int r = r0 + 8 * i;
    t[r][c] = src[(size_t)(ty0 + r) * Cc + tx0 + c];
  }
  __syncthreads();
#pragma unroll
  for (int i = 0; i < 4; i++) {
    int a = r0 + 8 * i;
    dst[(size_t)(tx0 + a) * R + ty0 + c] = (f16)t[c][a];
  }
}

// ============ 256x256 8-phase GEMM (m201 template, plain HIP) ============
// C[M][N] = A[M][K] * Bt[N][K]^T, f16 in/out. BK=64, 512 thr = 8 waves (2M x 4N).
// LDS 128K: 2 dbuf x [A-lo|A-hi|B-lo|B-hi] chunks (16K each, 128 rows x 64k).
// Chunk slot s (K-tile s>>2, chunk s&3, buf (s>>2)&1) staged at global phase s-5.
// XOR swizzle: LDS(row, slot16B) holds global col8 = slot ^ (row&7).
__global__ __launch_bounds__(512, 2) void gemm256_8ph_kernel(
    const f16* __restrict__ A, const f16* __restrict__ Bt, f16* __restrict__ C,
    int M, int N, int K) {
  __shared__ __align__(16) char smem[131072];
  const int tid = threadIdx.x;
  const int lane = tid & 63, wid = tid >> 6;
  const int wm = wid >> 2, wn = wid & 3;  // 2 x 4 waves, wave tile 128 x 64
  const int lo = lane & 15, hi = lane >> 4;

  // XCD-bijective block swizzle (grid % 8 == 0)
  const int ntn = N >> 8;
  const int nwg = (M >> 8) * ntn;
  const int wg = (blockIdx.x & 7) * (nwg >> 3) + (blockIdx.x >> 3);
  const int tm0 = (wg / ntn) << 8, tn0 = (wg % ntn) << 8;

  // staging coords: chunk row sr (+64 for 2nd issue), inverse-swizzled source slot
  const int sr = tid >> 3;
  const int sc8 = (tid & 7) ^ (sr & 7);

  // fragment LDS byte offsets (within chunk; +mi*2048 / +ni*2048 imm)
  const int sw = lo & 7;
  const int aoff0 = wm * 16384 + lo * 128 + ((hi ^ sw) << 4);          // ks=0
  const int aoff1 = wm * 16384 + lo * 128 + (((4 + hi) ^ sw) << 4);    // ks=1
  const int brow = ((wn & 1) * 64 + lo) * 128;
  const int boff0 = 32768 + (wn >> 1) * 16384 + brow + ((hi ^ sw) << 4);
  const int boff1 = 32768 + (wn >> 1) * 16384 + brow + (((4 + hi) ^ sw) << 4);

  f32x4 acc[8][4] = {};

  const int nslots = K >> 4;  // 4 chunks per 64-wide K-tile
  auto stage_slot = [&](int s) {
    if (s >= nslots) return;
    const int kt = s >> 2, ct = s & 3;
    char* dst = smem + (kt & 1) * 65536 + ct * 16384 + tid * 16;
    const f16* src = (ct < 2) ? (A + (size_t)(tm0 + (ct & 1) * 128) * K)
                              : (Bt + (size_t)(tn0 + (ct & 1) * 128) * K);
    const f16* p = src + (size_t)sr * K + kt * 64 + sc8 * 8;
    GLOAD_LDS16(p, dst);
    GLOAD_LDS16(p + ((size_t)K << 6), dst + 8192);
  };

  // K-tile = 4 phases; db = this tile's buffer; sb = first staging slot
  auto ktile4 = [&](const char* db, int sb) {
    f16x8 a[4][2], bA[2][2], bB[2][2];
    // ---- P0: read A rows 0..63 + B n-lo; MFMA (m-lo x n-lo) ----
    asm volatile("s_waitcnt vmcnt(2)" ::: "memory");
    __builtin_amdgcn_s_barrier();
#pragma unroll
    for (int mi = 0; mi < 4; mi++) {
      a[mi][0] = *(const f16x8*)(db + aoff0 + mi * 2048);
      a[mi][1] = *(const f16x8*)(db + aoff1 + mi * 2048);
    }
#pragma unroll
    for (int nn = 0; nn < 2; nn++) {
      bA[nn][0] = *(const f16x8*)(db + boff0 + nn * 2048);
      bA[nn][1] = *(const f16x8*)(db + boff1 + nn * 2048);
    }
    stage_slot(sb);
    __builtin_amdgcn_s_barrier();
    asm volatile("s_waitcnt lgkmcnt(0)" ::: "memory");
    __builtin_amdgcn_sched_barrier(0);
    __builtin_amdgcn_s_setprio(1);
#pragma unroll
    for (int mi = 0; mi < 4; mi++)
#pragma unroll
      for (int nn = 0; nn < 2; nn++) {
        acc[mi][nn] = MFMA32(a[mi][0], bA[nn][0], acc[mi][nn]);
        acc[mi][nn] = MFMA32(a[mi][1], bA[nn][1], acc[mi][nn]);
      }
    __builtin_amdgcn_s_setprio(0);
    // ---- P1: read B n-hi; MFMA (m-lo x n-hi) ----
    __builtin_amdgcn_s_barrier();
#pragma unroll
    for (int nn = 0; nn < 2; nn++) {
      bB[nn][0] = *(const f16x8*)(db + boff0 + (2 + nn) * 2048);
      bB[nn][1] = *(const f16x8*)(db + boff1 + (2 + nn) * 2048);
    }
    stage_slot(sb + 1);
    __builtin_amdgcn_s_barrier();
    asm volatile("s_waitcnt lgkmcnt(0)" ::: "memory");
    __builtin_amdgcn_sched_barrier(0);
    __builtin_amdgcn_s_setprio(1);
#pragma unroll
    for (int mi = 0; mi < 4; mi++)
#pragma unroll
      for (int nn = 0; nn < 2; nn++) {
        acc[mi][2 + nn] = MFMA32(a[mi][0], bB[nn][0], acc[mi][2 + nn]);
        acc[mi][2 + nn] = MFMA32(a[mi][1], bB[nn][1], acc[mi][2 + nn]);
      }
    __builtin_amdgcn_s_setprio(0);
    // ---- P2: read A rows 64..127; MFMA (m-hi x n-lo) ----
    __builtin_amdgcn_s_barrier();
#pragma unroll
    for (int mi = 0; mi < 4; mi++) {
      a[mi][0] = *(const f16x8*)(db + aoff0 + 8192 + mi * 2048);
      a[mi][1] = *(const f16x8*)(db + aoff1 + 8192 + mi * 2048);
    }
    stage_slot(sb + 2);
    __builtin_amdgcn_s_barrier();
    asm volatile("s_waitcnt lgkmcnt(0)" ::: "memory");
    __builtin_amdgcn_sched_barrier(0);
    __builtin_amdgcn_s_setprio(1);
#pragma unroll
    for (int mi = 0; mi < 4; mi++)
#pragma unroll
      for (int nn = 0; nn < 2; nn++) {
        acc[4 + mi][nn] = MFMA32(a[mi][0], bA[nn][0], acc[4 + mi][nn]);
        acc[4 + mi][nn] = MFMA32(a[mi][1], bA[nn][1], acc[4 + mi][nn]);
      }
    __builtin_amdgcn_s_setprio(0);
    // ---- P3: MFMA (m-hi x n-hi) ----
    __builtin_amdgcn_s_barrier();
    stage_slot(sb + 3);
    __builtin_amdgcn_s_barrier();
    __builtin_amdgcn_s_setprio(1);
#pragma unroll
    for (int mi = 0; mi < 4; mi++)
#pragma unroll
      for (int nn = 0; nn < 2; nn++) {
        acc[4 + mi][2 + nn] = MFMA32(a[mi][0], bB[nn][0], acc[4 + mi][2 + nn]);
        acc[4 + mi][2 + nn] = MFMA32(a[mi][1], bB[nn][1], acc[4 + mi][2 + nn]);
      }
    __builtin_amdgcn_s_setprio(0);
  };

  // prologue: stage slots 0..4 (K-tile0 + chunk0 of K-tile1)
  for (int s = 0; s < 5; s++) stage_slot(s);
  asm volatile("s_waitcnt vmcnt(2)" ::: "memory");
  __builtin_amdgcn_s_barrier();

  const int NI = K >> 7;  // 2 K-tiles per iteration
  for (int t = 0; t < NI; t++) {
    ktile4(smem, 8 * t + 5);
    ktile4(smem + 65536, 8 * t + 9);
  }

  // epilogue
#pragma unroll
  for (int mi = 0; mi < 8; mi++)
#pragma unroll
    for (int ni = 0; ni < 4; ni++)
#pragma unroll
      for (int r = 0; r < 4; r++) {
        int row = tm0 + wm * 128 + mi * 16 + 4 * hi + r;
        int col = tn0 + wn * 64 + ni * 16 + lo;
        C[(size_t)row * N + col] = (f16)acc[mi][ni][r];
      }
}

// ---------------- GEMM (128^2, triple-buffered counted vmcnt) — proj ----------------
template <bool OUT_F32>
__global__ __launch_bounds__(256) void gemm_f16_kernel(
    const f16* __restrict__ A, const f16* __restrict__ Bt, void* __restrict__ Cout,
    int M, int N, int K) {
  constexpr int BK = 32;
  __shared__ f16 Al[3][128 * BK];
  __shared__ f16 Bl[3][128 * BK];

  const int tid = threadIdx.x;
  const int lane = tid & 63, wid = tid >> 6;
  const int wm = wid >> 1, wn = wid & 1;
  const int lo = lane & 15, hi = lane >> 4;
  const int tn0 = blockIdx.x * 128, tm0 = blockIdx.y * 128;

  f32x4 acc[4][4] = {};

  const int r1 = tid >> 2, o1 = (tid & 3) * 8;

  auto stage = [&](int kt, int c) {
    GLOAD_LDS16(&A[(size_t)(tm0 + r1) * K + kt + o1], &Al[c][tid * 8]);
    GLOAD_LDS16(&A[(size_t)(tm0 + r1 + 64) * K + kt + o1], &Al[c][(tid + 256) * 8]);
    GLOAD_LDS16(&Bt[(size_t)(tn0 + r1) * K + kt + o1], &Bl[c][tid * 8]);
    GLOAD_LDS16(&Bt[(size_t)(tn0 + r1 + 64) * K + kt + o1], &Bl[c][(tid + 256) * 8]);
  };

  auto compute = [&](int cur) {
    f16x8 af[4], bf[4];
#pragma unroll
    for (int mi = 0; mi < 4; mi++)
      af[mi] = *(const f16x8*)&Al[cur][(wm * 64 + mi * 16 + lo) * BK + 8 * hi];
#pragma unroll
    for (int ni = 0; ni < 4; ni++)
      bf[ni] = *(const f16x8*)&Bl[cur][(wn * 64 + ni * 16 + lo) * BK + 8 * hi];
    __builtin_amdgcn_s_setprio(1);
#pragma unroll
    for (int mi = 0; mi < 4; mi++)
#pragma unroll
      for (int ni = 0; ni < 4; ni++)
        acc[mi][ni] = MFMA32(af[mi], bf[ni], acc[mi][ni]);
    __builtin_amdgcn_s_setprio(0);
  };

  const int NT = K / BK;
  stage(0, 0);
  stage(BK, 1);

  int cur = 0;
  for (int t = 0; t < NT - 1; t++) {
    asm volatile("s_waitcnt vmcnt(4)" ::: "memory");
    __builtin_amdgcn_s_barrier();
    if (t + 2 < NT) stage((t + 2) * BK, (t + 2) % 3);
    compute(cur);
    cur = (cur == 2) ? 0 : cur + 1;
  }
  asm volatile("s_waitcnt vmcnt(0)" ::: "memory");
  __builtin_amdgcn_s_barrier();
  compute(cur);

#pragma unroll
  for (int mi = 0; mi < 4; mi++)
#pragma unroll
    for (int ni = 0; ni < 4; ni++)
#pragma unroll
      for (int r = 0; r < 4; r++) {
        int row = tm0 + wm * 64 + mi * 16 + 4 * hi + r;
        int col = tn0 + wn * 64 + ni * 16 + lo;
        float v = acc[mi][ni][r];
        if (OUT_F32)
          ((float*)Cout)[(size_t)row * N + col] = v;
        else
          ((f16*)Cout)[(size_t)row * N + col] = (f16)v;
      }
}

// ---------------- causal flash attention ----------------
__global__ __launch_bounds__(256, 4) void attn_kernel(
    const f16* __restrict__ qkv, f16* __restrict__ y) {
  constexpr int T = 2048, NHD = 3072, LDO = 72;
  const int bh = blockIdx.x;
  const int b = bh >> 4, h = bh & 15;
  const int pr = blockIdx.y;
  const int tid = threadIdx.x;
  const int lane = tid & 63, w = tid >> 6;
  const int lo = lane & 15, hi = lane >> 4;

  const size_t base = (size_t)b * T * NHD + (size_t)h * 64;
  const f16* Qp = qkv + base;
  const f16* Kp = qkv + base + 1024;
  const f16* Vp = qkv + base + 2048;

  __shared__ __align__(16) char smem[32768];
  f16 (*Ol)[LDO] = (f16(*)[LDO])smem;

  const int tile[2] = {pr, 31 - pr};
  const int qb[2] = {tile[0] * 64 + w * 16, tile[1] * 64 + w * 16};

  const float scf = 0.125f * 1.44269504089f;
  f16x8 qf[2][2];
#pragma unroll
  for (int s = 0; s < 2; s++) {
    const f16* qrow = Qp + (size_t)(qb[s] + lo) * NHD;
#pragma unroll
    for (int ks = 0; ks < 2; ks++) {
      f16x8 v = *(const f16x8*)&qrow[ks * 32 + 8 * hi];
#pragma unroll
      for (int j = 0; j < 8; j++) v[j] = (f16)((float)v[j] * scf);
      qf[s][ks] = v;
    }
  }

  f32x4 oacc[2][4] = {};
  float mreg[2] = {-1e30f, -1e30f};
  float lsum[2] = {0.f, 0.f};

  const int kr = tid >> 3;
  const int kslot = (tid & 7) ^ (kr & 7);
  const int tp = tid & 127;
  const int vkey = 4 * (tp >> 3) + ((tp >> 1) & 3);
  const int vcol = (tid >> 7) * 16 + (tid & 1) * 8;

  const int kfo0 = lo * 64 + ((hi ^ (lo & 7)) * 8);
  const int kfo1 = lo * 64 + (((4 + hi) ^ (lo & 7)) * 8);

  auto stage = [&](int kv, int c) {
    char* kb = smem + c * 8192;
    char* vb = smem + 16384 + c * 8192;
    GLOAD_LDS16(&Kp[(size_t)(kv + kr) * NHD + kslot * 8], kb + tid * 16);
    GLOAD_LDS16(&Kp[(size_t)(kv + kr + 32) * NHD + kslot * 8], kb + 4096 + tid * 16);
    GLOAD_LDS16(&Vp[(size_t)(kv + vkey) * NHD + vcol], vb + tid * 16);
    GLOAD_LDS16(&Vp[(size_t)(kv + vkey) * NHD + vcol + 32], vb + 4096 + tid * 16);
  };

  const int nt = 32 - pr;
  stage(0, 0);
  asm volatile("s_waitcnt vmcnt(0)" ::: "memory");
  __builtin_amdgcn_s_barrier();

  for (int t = 0; t < nt; t++) {
    const int cur = t & 1;
    const int kv0 = t * 64;
    if (t + 1 < nt) stage(kv0 + 64, cur ^ 1);

    const f16* Kl = (const f16*)(smem + cur * 8192);
    const bool act0 = kv0 <= qb[0] + 15;

    f16x8 kf[2][4];
#pragma unroll
    for (int ct = 0; ct < 4; ct++) {
      kf[0][ct] = *(const f16x8*)&Kl[ct * 1024 + kfo0];
      kf[1][ct] = *(const f16x8*)&Kl[ct * 1024 + kfo1];
    }

    f16x4 pb[2][4];
#pragma unroll
    for (int s = 0; s < 2; s++) {
      if (s == 0 && !act0) continue;
      f32x4 s_[4] = {};
      __builtin_amdgcn_s_setprio(1);
#pragma unroll
      for (int ks = 0; ks < 2; ks++)
#pragma unroll
        for (int ct = 0; ct < 4; ct++)
          s_[ct] = MFMA32(kf[ks][ct], qf[s][ks], s_[ct]);
      __builtin_amdgcn_s_setprio(0);

      if (kv0 + 63 > qb[s]) {
        const int q = qb[s] + lo;
#pragma unroll
        for (int ct = 0; ct < 4; ct++)
#pragma unroll
          for (int r = 0; r < 4; r++)
            if (kv0 + ct * 16 + 4 * hi + r > q) s_[ct][r] = -3.0e38f;
      }
      float mt = -3.0e38f;
#pragma unroll
      for (int ct = 0; ct < 4; ct++)
        mt = fmaxf(mt, fmaxf(fmaxf(s_[ct][0], s_[ct][1]), fmaxf(s_[ct][2], s_[ct][3])));
      mt = fmaxf(mt, __shfl_xor(mt, 16));
      mt = fmaxf(mt, __shfl_xor(mt, 32));
      float mn = mreg[s];
      if (!__all(mt <= mn + 8.f)) {
        mn = fmaxf(mn, mt);
        const float al = EXP2(mreg[s] - mn);
        mreg[s] = mn;
        lsum[s] *= al;
#pragma unroll
        for (int ct = 0; ct < 4; ct++)
#pragma unroll
          for (int r = 0; r < 4; r++) oacc[s][ct][r] *= al;
      }
      float rs = 0.f;
#pragma unroll
      for (int ct = 0; ct < 4; ct++)
#pragma unroll
        for (int r = 0; r < 4; r++) {
          float p = EXP2(s_[ct][r] - mn);
          rs += p;
          pb[s][ct][r] = (f16)p;
        }
      rs += __shfl_xor(rs, 16);
      rs += __shfl_xor(rs, 32);
      lsum[s] += rs;
    }

    lds_cp vtrb = (lds_cp)(smem + 16384 + cur * 8192) + lane * 8;
#pragma unroll
    for (int ct = 0; ct < 4; ct++) {
      lds_cp bct = vtrb + ct * 2048;
      f16x4 v0, v1, v2, v3;
      TR16(v0, bct, "0");
      TR16(v1, bct, "512");
      TR16(v2, bct, "1024");
      TR16(v3, bct, "1536");
      asm volatile("s_waitcnt lgkmcnt(0)" ::: "memory");
      __builtin_amdgcn_sched_barrier(0);
      __builtin_amdgcn_s_setprio(1);
      if (act0) {
        oacc[0][ct] = MFMA16(v0, pb[0][0], oacc[0][ct]);
        oacc[0][ct] = MFMA16(v1, pb[0][1], oacc[0][ct]);
        oacc[0][ct] = MFMA16(v2, pb[0][2], oacc[0][ct]);
        oacc[0][ct] = MFMA16(v3, pb[0][3], oacc[0][ct]);
      }
      oacc[1][ct] = MFMA16(v0, pb[1][0], oacc[1][ct]);
      oacc[1][ct] = MFMA16(v1, pb[1][1], oacc[1][ct]);
      oacc[1][ct] = MFMA16(v2, pb[1][2], oacc[1][ct]);
      oacc[1][ct] = MFMA16(v3, pb[1][3], oacc[1][ct]);
      __builtin_amdgcn_s_setprio(0);
    }

    asm volatile("s_waitcnt vmcnt(0)" ::: "memory");
    __builtin_amdgcn_s_barrier();
  }

#pragma unroll
  for (int s = 0; s < 2; s++) {
    __syncthreads();
    const float inv = 1.f / lsum[s];
#pragma unroll
    for (int ct = 0; ct < 4; ct++) {
      f16x4 o4;
#pragma unroll
      for (int r = 0; r < 4; r++) o4[r] = (f16)(oacc[s][ct][r] * inv);
      *(f16x4*)&Ol[w * 16 + lo][ct * 16 + 4 * hi] = o4;
    }
    __syncthreads();
#pragma unroll
    for (int i = 0; i < 2; i++) {
      int idx = tid + 256 * i;
      int qq = idx >> 3, ch = idx & 7;
      *(f16x8*)&y[((size_t)b * T + tile[s] * 64 + qq) * 1024 + (size_t)h * 64 + ch * 8] =
          *(const f16x8*)&Ol[qq][ch * 8];
    }
  }
}

extern "C" void kernel_launch(void* const* d_in, const int* in_sizes, int n_in,
                              void* d_out, int out_size, void* d_ws, size_t ws_size,
                              hipStream_t stream) {
  const float* x = (const float*)d_in[0];
  const float* w_qkv = (const float*)d_in[2];
  const float* w_proj = (const float*)d_in[3];

  constexpr int B = 4, T = 2048, C = 1024, NH = 16;
  constexpr int M = B * T;   // 8192
  constexpr int N1 = 3 * C;  // 3072

  char* ws = (char*)d_ws;
  f16* x16 = (f16*)ws;    ws += (size_t)M * C * 2;
  f16* wqkvT = (f16*)ws;  ws += (size_t)N1 * C * 2;
  f16* wprojT = (f16*)ws; ws += (size_t)C * C * 2;
  f16* qkvb = (f16*)ws;   ws += (size_t)M * N1 * 2;
  f16* y16 = (f16*)ws;

  cast_f32_f16_kernel<<<(M * C / 4 + 255) / 256, 256, 0, stream>>>(x, x16, M * C / 4);
  transpose_cast_kernel<<<dim3(N1 / 32, C / 32), 256, 0, stream>>>(w_qkv, wqkvT, C, N1);
  transpose_cast_kernel<<<dim3(C / 32, C / 32), 256, 0, stream>>>(w_proj, wprojT, C, C);
  gemm256_8ph_kernel<<<(M / 256) * (N1 / 256), 512, 0, stream>>>(x16, wqkvT, qkvb, M, N1, C);
  attn_kernel<<<dim3(B * NH, 16), 256, 0, stream>>>(qkvb, y16);
  gemm_f16_kernel<true><<<dim3(C / 128, M / 128), 256, 0, stream>>>(y16, wprojT, (float*)d_out, M, C, C);
}